// Round 4
// baseline (1014.847 us; speedup 1.0000x reference)
//
#include <hip/hip_runtime.h>

// ---------------------------------------------------------------------------
// MambaLayer on MI355X (gfx950).
// conv3d -> inorm(+lrelu) -> conv3d -> inorm(+res) -> scrambled reshape + LN
// -> in_proj GEMM -> depthwise conv1d+silu -> x_proj GEMM -> softplus(dt)
// -> chunked selective scan -> gate -> out_proj GEMM.
// Round-4: conv3d K-loop restructured: dw-tap fusion (130-row A window, 18
// stages, 36 barriers vs 108), VGPR prefetch pipeline overlapping global
// latency with MFMA, lane-linear conflict-free staging (Al 104 / Bl 100).
// ---------------------------------------------------------------------------

typedef unsigned short u16;
typedef __attribute__((ext_vector_type(8))) short bf16x8;
typedef __attribute__((ext_vector_type(4))) float f4;

#define MTOT 32768

__device__ __forceinline__ float b2f(u16 v){ return __uint_as_float(((unsigned)v)<<16); }
__device__ __forceinline__ u16 f2b(float f){
  unsigned u = __float_as_uint(f);
  return (u16)((u + 0x7fffu + ((u>>16)&1u)) >> 16);      // RNE
}
__device__ __forceinline__ float blo(unsigned v){ return __uint_as_float(v<<16); }
__device__ __forceinline__ float bhi(unsigned v){ return __uint_as_float(v & 0xffff0000u); }
__device__ __forceinline__ unsigned pack2(float a, float b){
  return (unsigned)f2b(a) | ((unsigned)f2b(b)<<16);
}

// --------------------------------------------------------------------- init
__global__ __launch_bounds__(256) void k_init(int* cnt, float* zp, float* stats){
  int i = blockIdx.x*256 + threadIdx.x;
  if (i == 0)   *cnt = 0;
  if (i < 128)  zp[i] = 0.f;
  if (i < 3072) stats[i] = 0.f;
}

__global__ void k_diag(float* o, float v){
  o[0] = v; o[1] = v;
  ((u16*)o)[4] = f2b(v); ((u16*)o)[5] = f2b(v);
}

// --------------------------------------------------------- dtype probe
__global__ __launch_bounds__(256) void k_probe(const u16* __restrict__ x, int* cnt){
  int t = threadIdx.x;
  int c = 0;
  #pragma unroll
  for (int i=0;i<16;i++){
    u16 v = x[t*16 + i];
    if (((v>>7)&0xFF) >= 0x90) c++;
  }
  if (c) atomicAdd(cnt, c);
}

// ----------------------------------------------------- canonical bf16 cvt
__global__ __launch_bounds__(256) void k_cvt(const void* __restrict__ src, u16* __restrict__ dst,
                                             int n, const int* __restrict__ cnt){
  const int gid = blockIdx.x*256 + threadIdx.x;
  if (gid*8 >= n) return;
  if (*cnt > 64){
    const float4* s = (const float4*)src;
    float4 a = s[gid*2], b = s[gid*2+1];
    *(uint4*)(dst + gid*8) = make_uint4(pack2(a.x,a.y), pack2(a.z,a.w),
                                        pack2(b.x,b.y), pack2(b.z,b.w));
  } else {
    ((uint4*)dst)[gid] = ((const uint4*)src)[gid];
  }
}

struct SmallCvt { const void* src[13]; int n[13]; int off[13]; };

__global__ __launch_bounds__(256) void k_cvt_small(SmallCvt sc, u16* __restrict__ wc,
                                                   const int* __restrict__ cnt){
  const int t = blockIdx.y;
  const int gid = blockIdx.x*256 + threadIdx.x;
  const int n = sc.n[t];
  if (gid*8 >= n) return;
  u16* dst = wc + sc.off[t];
  if (*cnt > 64){
    const float4* s = (const float4*)sc.src[t];
    float4 a = s[gid*2], b = s[gid*2+1];
    *(uint4*)(dst + gid*8) = make_uint4(pack2(a.x,a.y), pack2(a.z,a.w),
                                        pack2(b.x,b.y), pack2(b.z,b.w));
  } else {
    *(uint4*)(dst + gid*8) = ((const uint4*)sc.src[t])[gid];
  }
}

// ------------------------------------------------- conv weight permutation
__global__ __launch_bounds__(256) void k_wt(const void* __restrict__ w1, const void* __restrict__ w2,
                                            u16* __restrict__ b1, u16* __restrict__ b2,
                                            const int* __restrict__ cnt){
  int gid = blockIdx.x*256 + threadIdx.x;
  if (gid >= 2*995328) return;
  const bool f32 = *cnt > 64;
  int sel = gid >= 995328 ? 1 : 0;
  int lo  = gid - sel*995328;
  int co = lo / 5184, rr = lo % 5184;
  int p  = rr / 192,  ci = rr % 192;
  const void* s = sel ? w2 : w1;
  const int si = (co*192 + ci)*27 + p;
  u16 v = f32 ? f2b(((const float*)s)[si]) : ((const u16*)s)[si];
  (sel ? b2 : b1)[lo] = v;
}

// ------------------------------------------------------ conv3d shift-GEMM
// M=32768 (b,t,h,w), N=192 (co), K=27 taps x 192 ci. BM=128 BN=64.
// dw-fused: per (dt,dh) stage a 130-row A window + B for 3 taps; 2 K-halves.
// VGPR prefetch pipeline; lane-linear staging writes; Al stride 104, Bl 100.
__global__ __launch_bounds__(256,2) void k_conv(const u16* __restrict__ X, const u16* __restrict__ Bw,
                                                const u16* __restrict__ bias, u16* __restrict__ outc,
                                                float* __restrict__ sumG, float* __restrict__ sqG){
  __shared__ u16 Al[130*104];   // 27,040 B  (window rows m0-1 .. m0+128)
  __shared__ u16 Bl[192*100];   // 38,400 B  (3 taps x 64 n-rows)
  const int tid = threadIdx.x;
  const int m0 = blockIdx.x*128, n0 = blockIdx.y*64;
  const int bb = blockIdx.x >> 7;
  const int rem0 = m0 & 16383;
  const int t0 = rem0 >> 10, h0 = (rem0 >> 5) & 31;   // block-uniform; h rows h0..h0+3
  const int lane = tid&63, wv = tid>>6, wm = wv>>1, wn = wv&1, lr = lane&15, q = lane>>4;

  // thread-const chunk tables (lane-linear => conflict-free staging writes)
  int aoffG[7], awr[7];
  #pragma unroll
  for (int j=0;j<7;j++){
    const int cid = j*256 + tid;          // 1560 chunks = 130 rows x 12
    const int rw = cid/12, cc = cid%12;
    aoffG[j] = (rw-1)*192 + cc*8;         // global, relative to shifted base
    awr[j]   = rw*104 + cc*8;             // LDS
  }
  int boffG[9], bwr[9];
  #pragma unroll
  for (int j=0;j<9;j++){
    const int cid = j*256 + tid;          // 2304 chunks = 192 rows x 12
    const int rw = cid/12, cc = cid%12;   // rw = tap*64 + n
    boffG[j] = (n0 + (rw & 63))*5184 + (rw >> 6)*192 + cc*8;
    bwr[j]   = rw*100 + cc*8;
  }

  const f4 z4 = {0.f,0.f,0.f,0.f};
  const bf16x8 z8 = {0,0,0,0,0,0,0,0};
  f4 acc[4][2];
  #pragma unroll
  for (int i=0;i<4;i++){
    #pragma unroll
    for (int j=0;j<2;j++) acc[i][j] = z4;
  }

  uint4 ra[7], rb[9];
  auto prefetch = [&](int s){
    const int dtdh = s>>1, sub = s&1;
    const int dt = dtdh/3 - 1, dh = dtdh%3 - 1;
    const u16* As = X + (ptrdiff_t)(m0 + dt*1024 + dh*32)*192 + sub*96;
    #pragma unroll
    for (int j=0;j<7;j++)
      if (j<6 || tid<24) ra[j] = *(const uint4*)(As + aoffG[j]);
    const u16* Bs = Bw + dtdh*3*192 + sub*96;
    #pragma unroll
    for (int j=0;j<9;j++) rb[j] = *(const uint4*)(Bs + boffG[j]);
  };

  prefetch(0);
  for (int s=0; s<18; ++s){
    __syncthreads();                       // prev stage's LDS reads done
    #pragma unroll
    for (int j=0;j<7;j++) if (j<6 || tid<24) *(uint4*)&Al[awr[j]] = ra[j];
    #pragma unroll
    for (int j=0;j<9;j++) *(uint4*)&Bl[bwr[j]] = rb[j];
    __syncthreads();                       // staging visible
    if (s < 17) prefetch(s+1);             // overlap next loads with MFMA
    const int dtdh = s>>1;
    const int dt = dtdh/3 - 1, dh = dtdh%3 - 1;
    const bool tval = ((unsigned)(t0 + dt) < 16u);
    const bool hv0 = ((unsigned)(h0 + wm*2     + dh) < 32u);  // frags i=0,1
    const bool hv1 = ((unsigned)(h0 + wm*2 + 1 + dh) < 32u);  // frags i=2,3
    if (tval){
      #pragma unroll
      for (int kt=0; kt<3; ++kt){
        bf16x8 bv[3][2];
        #pragma unroll
        for (int tp=0;tp<3;tp++){
          #pragma unroll
          for (int j=0;j<2;j++)
            bv[tp][j] = *(const bf16x8*)&Bl[(tp*64 + wn*32 + j*16 + lr)*100 + kt*32 + q*8];
        }
        #pragma unroll
        for (int i=0;i<4;i++){
          const bool hok = (i<2) ? hv0 : hv1;
          if (!hok) continue;
          const int crow = wm*64 + i*16 + lr;     // central row; w = crow&31
          #pragma unroll
          for (int tp=0;tp<3;tp++){               // dw = tp-1; window row = crow+tp
            bf16x8 av = *(const bf16x8*)&Al[(crow + tp)*104 + kt*32 + q*8];
            if (tp==0 && (i&1)==0) av = (lr==0)  ? z8 : av;   // w=0, dw=-1
            if (tp==2 && (i&1)==1) av = (lr==15) ? z8 : av;   // w=31, dw=+1
            acc[i][0] = __builtin_amdgcn_mfma_f32_16x16x32_bf16(av, bv[tp][0], acc[i][0], 0,0,0);
            acc[i][1] = __builtin_amdgcn_mfma_f32_16x16x32_bf16(av, bv[tp][1], acc[i][1], 0,0,0);
          }
        }
      }
    }
  }

  float psum[2] = {0.f,0.f}, psq[2] = {0.f,0.f};
  #pragma unroll
  for (int j=0;j<2;j++){
    const int col = n0 + wn*32 + j*16 + lr;
    const float bvl = b2f(bias[col]);
    #pragma unroll
    for (int i=0;i<4;i++){
      const int row0 = m0 + wm*64 + i*16 + q*4;
      #pragma unroll
      for (int g=0; g<4; ++g){
        const float v = acc[i][j][g] + bvl;
        outc[(size_t)(row0+g)*192 + col] = f2b(v);
        psum[j] += v; psq[j] += v*v;
      }
    }
  }
  __syncthreads();
  float* red = (float*)Al;
  if (tid < 128) red[tid] = 0.f;
  __syncthreads();
  #pragma unroll
  for (int j=0;j<2;j++){
    const int cl = wn*32 + j*16 + lr;
    atomicAdd(&red[cl], psum[j]);
    atomicAdd(&red[64+cl], psq[j]);
  }
  __syncthreads();
  if (tid < 64){
    atomicAdd(&sumG[bb*192 + n0 + tid], red[tid]);
    atomicAdd(&sqG[bb*192 + n0 + tid], red[64+tid]);
  }
}

// --------------------------------------------------- generic GEMM (B^T in)
template<int EPI>
__global__ __launch_bounds__(256) void k_gemm(const u16* __restrict__ A, const u16* __restrict__ Bm,
                                              const int K, const int NB,
                                              void* __restrict__ o0, void* __restrict__ o1,
                                              const u16* __restrict__ zp,
                                              const int* __restrict__ cnt){
  __shared__ u16 Al[128*104];
  __shared__ u16 Bl[64*104];
  const int tid = threadIdx.x;
  const int m0 = blockIdx.x*128, n0 = blockIdx.y*64;
  const int r = tid>>1, half = tid&1;
  const u16* arow = A + ((size_t)(m0+r)*K + half*48);
  const int bn = tid>>2, bk = tid&3;
  const bool bval = (n0+bn) < NB;
  const u16* brow = Bm + ((size_t)(n0+bn)*K + bk*24);
  const int lane = tid&63, wv = tid>>6, wm = wv>>1, wn = wv&1, lr = lane&15, q = lane>>4;
  const f4 z4 = {0.f,0.f,0.f,0.f};
  f4 acc[4][2];
  #pragma unroll
  for (int i=0;i<4;i++){
    #pragma unroll
    for (int j=0;j<2;j++) acc[i][j] = z4;
  }
  for (int k0=0; k0<K; k0+=96){
    const u16* as = arow + k0;
    const u16* bs = bval ? (brow + k0) : zp;
    __syncthreads();
    #pragma unroll
    for (int i=0;i<6;i++)
      *(uint4*)&Al[r*104 + half*48 + i*8] = *(const uint4*)(as + i*8);
    #pragma unroll
    for (int i=0;i<3;i++)
      *(uint4*)&Bl[bn*104 + bk*24 + i*8] = *(const uint4*)(bs + i*8);
    __syncthreads();
    #pragma unroll
    for (int kt=0; kt<3; ++kt){
      bf16x8 av[4], bv[2];
      #pragma unroll
      for (int i=0;i<4;i++) av[i] = *(const bf16x8*)&Al[(wm*64 + i*16 + lr)*104 + kt*32 + q*8];
      #pragma unroll
      for (int j=0;j<2;j++) bv[j] = *(const bf16x8*)&Bl[(wn*32 + j*16 + lr)*104 + kt*32 + q*8];
      #pragma unroll
      for (int i=0;i<4;i++){
        #pragma unroll
        for (int j=0;j<2;j++)
          acc[i][j] = __builtin_amdgcn_mfma_f32_16x16x32_bf16(av[i], bv[j], acc[i][j], 0,0,0);
      }
    }
  }
  const bool f32o = (EPI == 2) && (*cnt > 64);
  #pragma unroll
  for (int j=0;j<2;j++){
    const int col = n0 + wn*32 + j*16 + lr;
    #pragma unroll
    for (int i=0;i<4;i++){
      const int row0 = m0 + wm*64 + i*16 + q*4;
      #pragma unroll
      for (int g=0; g<4; ++g){
        const int row = row0 + g;
        const float v = acc[i][j][g];
        if (EPI == 0){
          if (col < 384) ((u16*)o0)[(size_t)row*384 + col] = f2b(v);
          else           ((u16*)o1)[(size_t)row*384 + (col-384)] = f2b(v);
        } else if (EPI == 1){
          if (col < 44)  ((float*)o0)[(size_t)row*44 + col] = v;
        } else {
          if (f32o) ((float*)o0)[(size_t)row*192 + col] = v;
          else      ((u16*) o0)[(size_t)row*192 + col] = f2b(v);
        }
      }
    }
  }
}

// ----------------------------------------------------- instance norm final
__global__ __launch_bounds__(384) void k_infin(const float* __restrict__ s, const float* __restrict__ s2,
                                               float* __restrict__ mr){
  const int i = threadIdx.x;
  const float mean = s[i]*(1.f/16384.f);
  const float var  = s2[i]*(1.f/16384.f) - mean*mean;
  mr[i]     = mean;
  mr[384+i] = rsqrtf(var + 1e-5f);
}

// mode 1: lrelu(norm) -> bf16 ; mode 2: norm + residual(bf16) -> bf16
__global__ __launch_bounds__(256) void k_inapply(const u16* __restrict__ craw, const float* __restrict__ mr,
                                                 const u16* __restrict__ resid, u16* __restrict__ outp,
                                                 const int mode){
  const int gid = blockIdx.x*256 + threadIdx.x;
  const size_t base = (size_t)gid*8;
  const int mrow = gid/24;
  const int c0 = (gid%24)*8;
  const int b = mrow >> 14;
  const uint4 rv = *(const uint4*)(craw + base);
  float vv[8] = {blo(rv.x),bhi(rv.x),blo(rv.y),bhi(rv.y),blo(rv.z),bhi(rv.z),blo(rv.w),bhi(rv.w)};
  uint4 xv;
  float rr[8];
  if (mode == 2){
    xv = *(const uint4*)(resid + base);
    rr[0]=blo(xv.x); rr[1]=bhi(xv.x); rr[2]=blo(xv.y); rr[3]=bhi(xv.y);
    rr[4]=blo(xv.z); rr[5]=bhi(xv.z); rr[6]=blo(xv.w); rr[7]=bhi(xv.w);
  }
  unsigned pk[4];
  #pragma unroll
  for (int k2=0;k2<4;k2++){
    const int c = c0 + 2*k2;
    float a0 = (vv[2*k2]   - mr[b*192+c])  * mr[384 + b*192 + c];
    float a1 = (vv[2*k2+1] - mr[b*192+c+1])* mr[384 + b*192 + c+1];
    if (mode == 1){ a0 = a0 > 0.f ? a0 : 0.01f*a0; a1 = a1 > 0.f ? a1 : 0.01f*a1; }
    else          { a0 += rr[2*k2]; a1 += rr[2*k2+1]; }
    pk[k2] = pack2(a0, a1);
  }
  *(uint4*)(outp + base) = make_uint4(pk[0],pk[1],pk[2],pk[3]);
}

// ------------------------------------- scrambled reshape + LayerNorm(192)
__global__ __launch_bounds__(128) void k_ln(const u16* __restrict__ F, const u16* __restrict__ g,
                                            const u16* __restrict__ bb, u16* __restrict__ xn){
  __shared__ u16 S[192*128];
  const int tid = threadIdx.x;
  const int b = blockIdx.y;
  const int l0 = blockIdx.x*128;
  const u16* Fb = F + (size_t)b*3145728;
  for (int qi = tid; qi < 3072; qi += 128){
    int c = qi >> 4, o = (qi & 15)*8;
    *(uint4*)&S[c*128 + o] = *(const uint4*)(Fb + (size_t)c*16384 + l0 + o);
  }
  __syncthreads();
  float sum = 0.f, sq = 0.f;
  for (int c=0;c<192;c++){ float v = b2f(S[c*128 + tid]); sum += v; sq += v*v; }
  const float mean = sum*(1.f/192.f);
  const float rs = rsqrtf(sq*(1.f/192.f) - mean*mean + 1e-5f);
  u16* dst = xn + ((size_t)(b*16384 + l0 + tid))*192;
  for (int c0=0;c0<192;c0+=8){
    unsigned pk[4];
    #pragma unroll
    for (int k2=0;k2<4;k2++){
      int c = c0 + 2*k2;
      float v0 = (b2f(S[(c  )*128+tid]) - mean)*rs*b2f(g[c  ]) + b2f(bb[c  ]);
      float v1 = (b2f(S[(c+1)*128+tid]) - mean)*rs*b2f(g[c+1]) + b2f(bb[c+1]);
      pk[k2] = pack2(v0, v1);
    }
    *(uint4*)(dst + c0) = make_uint4(pk[0],pk[1],pk[2],pk[3]);
  }
}

// ----------------------------------- causal depthwise conv1d (w=4) + silu
__global__ __launch_bounds__(256) void k_conv1d(const u16* __restrict__ u, const u16* __restrict__ w,
                                                const u16* __restrict__ bias, u16* __restrict__ up){
  const int gid = blockIdx.x*256 + threadIdx.x;
  const int mrow = gid/48, d8 = (gid%48)*8;
  const int l = mrow & 16383;
  float acc[8];
  #pragma unroll
  for (int k=0;k<8;k++) acc[k] = b2f(bias[d8+k]);
  float wk[4][8];
  #pragma unroll
  for (int dd=0;dd<8;dd++){
    uint2 tw = *(const uint2*)(w + (size_t)(d8+dd)*4);
    wk[0][dd]=blo(tw.x); wk[1][dd]=bhi(tw.x); wk[2][dd]=blo(tw.y); wk[3][dd]=bhi(tw.y);
  }
  #pragma unroll
  for (int k=0;k<4;k++){
    if (l - 3 + k < 0) continue;
    uint4 tv = *(const uint4*)(u + ((size_t)(mrow-3+k))*384 + d8);
    float uv[8] = {blo(tv.x),bhi(tv.x),blo(tv.y),bhi(tv.y),blo(tv.z),bhi(tv.z),blo(tv.w),bhi(tv.w)};
    #pragma unroll
    for (int dd=0;dd<8;dd++) acc[dd] += uv[dd]*wk[k][dd];
  }
  unsigned pk[4];
  #pragma unroll
  for (int k2=0;k2<4;k2++){
    float a0 = acc[2*k2], a1 = acc[2*k2+1];
    a0 = a0/(1.f + __expf(-a0));
    a1 = a1/(1.f + __expf(-a1));
    pk[k2] = pack2(a0, a1);
  }
  *(uint4*)(up + (size_t)mrow*384 + d8) = make_uint4(pk[0],pk[1],pk[2],pk[3]);
}

// --------------------------------------------- selective scan, chunked
// thread-per-d, 16 states in registers. 256 chunks x 64 steps.
__global__ __launch_bounds__(192) void k_scan1(const float* __restrict__ xdb, const u16* __restrict__ up,
                                               const u16* __restrict__ dtw, const u16* __restrict__ dtb,
                                               const u16* __restrict__ alog,
                                               float* __restrict__ P, float* __restrict__ Q){
  __shared__ float xdbS[64*44];
  const int tid = threadIdx.x;
  const int chunk = blockIdx.x, b = blockIdx.y;
  const int d = blockIdx.z*192 + tid;
  const size_t mbase = (size_t)b*16384 + chunk*64;
  const float* xs = xdb + mbase*44;
  for (int qi=tid; qi<704; qi+=192)
    *(float4*)&xdbS[qi*4] = *(const float4*)(xs + (size_t)qi*4);
  float w[12];
  #pragma unroll
  for (int i=0;i<12;i++) w[i] = b2f(dtw[d*12+i]);
  const float dtbv = b2f(dtb[d]);
  float Av[16];
  #pragma unroll
  for (int s=0;s<16;s++) Av[s] = -__expf(b2f(alog[d*16+s]));
  float pp[16], qq[16];
  #pragma unroll
  for (int s=0;s<16;s++){ pp[s]=1.f; qq[s]=0.f; }
  const u16* uptr = up + mbase*384 + d;
  __syncthreads();
  for (int l=0;l<64;l++){
    const float* row = &xdbS[l*44];
    const float4 r0 = *(const float4*)(row);
    const float4 r1 = *(const float4*)(row+4);
    const float4 r2 = *(const float4*)(row+8);
    float a = dtbv + r0.x*w[0]+r0.y*w[1]+r0.z*w[2]+r0.w*w[3]
                   + r1.x*w[4]+r1.y*w[5]+r1.z*w[6]+r1.w*w[7]
                   + r2.x*w[8]+r2.y*w[9]+r2.z*w[10]+r2.w*w[11];
    const float dl = a > 20.f ? a : __logf(1.f + __expf(a));
    const float uv = b2f(uptr[(size_t)l*384]);
    const float dlu = dl*uv;
    const float4 B0 = *(const float4*)(row+12);
    const float4 B1 = *(const float4*)(row+16);
    const float4 B2 = *(const float4*)(row+20);
    const float4 B3 = *(const float4*)(row+24);
    const float Bv[16] = {B0.x,B0.y,B0.z,B0.w,B1.x,B1.y,B1.z,B1.w,
                          B2.x,B2.y,B2.z,B2.w,B3.x,B3.y,B3.z,B3.w};
    #pragma unroll
    for (int s=0;s<16;s++){
      const float as = __expf(dl*Av[s]);
      pp[s] *= as;
      qq[s] = as*qq[s] + dlu*Bv[s];
    }
  }
  const size_t o = (((size_t)b*256 + chunk)*384 + d)*16;
  float* Po = P + o; float* Qo = Q + o;
  *(float4*)(Po+ 0) = make_float4(pp[0],pp[1],pp[2],pp[3]);
  *(float4*)(Po+ 4) = make_float4(pp[4],pp[5],pp[6],pp[7]);
  *(float4*)(Po+ 8) = make_float4(pp[8],pp[9],pp[10],pp[11]);
  *(float4*)(Po+12) = make_float4(pp[12],pp[13],pp[14],pp[15]);
  *(float4*)(Qo+ 0) = make_float4(qq[0],qq[1],qq[2],qq[3]);
  *(float4*)(Qo+ 4) = make_float4(qq[4],qq[5],qq[6],qq[7]);
  *(float4*)(Qo+ 8) = make_float4(qq[8],qq[9],qq[10],qq[11]);
  *(float4*)(Qo+12) = make_float4(qq[12],qq[13],qq[14],qq[15]);
}

__global__ __launch_bounds__(256) void k_scan2(const float* __restrict__ P, const float* __restrict__ Q,
                                               float* __restrict__ hin){
  const int gid = blockIdx.x*256 + threadIdx.x;      // 12288
  const int b = gid / 6144, ds = gid % 6144;
  const size_t base = (size_t)b*1572864 + ds;
  float h = 0.f;
  for (int g2=0; g2<256; ++g2){
    const size_t idx = base + (size_t)g2*6144;
    hin[idx] = h;
    h = P[idx]*h + Q[idx];
  }
}

__global__ __launch_bounds__(192) void k_scan3(const float* __restrict__ xdb, const u16* __restrict__ up,
                                               const u16* __restrict__ zb,
                                               const u16* __restrict__ dtw, const u16* __restrict__ dtb,
                                               const u16* __restrict__ alog, const u16* __restrict__ dp,
                                               const float* __restrict__ hin, u16* __restrict__ yg){
  __shared__ float xdbS[64*44];
  const int tid = threadIdx.x;
  const int chunk = blockIdx.x, b = blockIdx.y;
  const int d = blockIdx.z*192 + tid;
  const size_t mbase = (size_t)b*16384 + chunk*64;
  const float* xs = xdb + mbase*44;
  for (int qi=tid; qi<704; qi+=192)
    *(float4*)&xdbS[qi*4] = *(const float4*)(xs + (size_t)qi*4);
  float w[12];
  #pragma unroll
  for (int i=0;i<12;i++) w[i] = b2f(dtw[d*12+i]);
  const float dtbv = b2f(dtb[d]);
  float Av[16];
  #pragma unroll
  for (int s=0;s<16;s++) Av[s] = -__expf(b2f(alog[d*16+s]));
  const float Dv = b2f(dp[d]);
  float h[16];
  {
    const float* hi = hin + (((size_t)b*256 + chunk)*384 + d)*16;
    const float4 h0 = *(const float4*)(hi+0);
    const float4 h1 = *(const float4*)(hi+4);
    const float4 h2 = *(const float4*)(hi+8);
    const float4 h3 = *(const float4*)(hi+12);
    h[0]=h0.x;h[1]=h0.y;h[2]=h0.z;h[3]=h0.w;
    h[4]=h1.x;h[5]=h1.y;h[6]=h1.z;h[7]=h1.w;
    h[8]=h2.x;h[9]=h2.y;h[10]=h2.z;h[11]=h2.w;
    h[12]=h3.x;h[13]=h3.y;h[14]=h3.z;h[15]=h3.w;
  }
  const u16* uptr = up + mbase*384 + d;
  const u16* zptr = zb + mbase*384 + d;
  u16* yptr = yg + mbase*384 + d;
  __syncthreads();
  for (int l=0;l<64;l++){
    const float* row = &xdbS[l*44];
    const float4 r0 = *(const float4*)(row);
    const float4 r1 = *(const float4*)(row+4);
    const float4 r2 = *(const float4*)(row+8);
    float a = dtbv + r0.x*w[0]+r0.y*w[1]+r0.z*w[2]+r0.w*w[3]
                   + r1.x*w[4]+r1.y*w[5]+r1.z*w[6]+r1.w*w[7]
                   + r2.x*w[8]+r2.y*w[9]+r2.z*w[10]+r2.w*w[11];
    const float dl = a > 20.f ? a : __logf(1.f + __expf(a));
    const float uv = b2f(uptr[(size_t)l*384]);
    const float dlu = dl*uv;
    const float4 B0 = *(const float4*)(row+12);
    const float4 B1 = *(const float4*)(row+16);
    const float4 B2 = *(const float4*)(row+20);
    const float4 B3 = *(const float4*)(row+24);
    const float4 C0 = *(const float4*)(row+28);
    const float4 C1 = *(const float4*)(row+32);
    const float4 C2 = *(const float4*)(row+36);
    const float4 C3 = *(const float4*)(row+40);
    const float Bv[16] = {B0.x,B0.y,B0.z,B0.w,B1.x,B1.y,B1.z,B1.w,
                          B2.x,B2.y,B2.z,B2.w,B3.x,B3.y,B3.z,B3.w};
    const float Cv[16] = {C0.x,C0.y,C0.z,C0.w,C1.x,C1.y,C1.z,C1.w,
                          C2.x,C2.y,C2.z,C2.w,C3.x,C3.y,C3.z,C3.w};
    float ct = 0.f;
    #pragma unroll
    for (int s=0;s<16;s++){
      const float as = __expf(dl*Av[s]);
      h[s] = as*h[s] + dlu*Bv[s];
      ct += h[s]*Cv[s];
    }
    const float yv = ct + uv*Dv;
    const float zv = b2f(zptr[(size_t)l*384]);
    yptr[(size_t)l*384] = f2b(yv * (zv/(1.f + __expf(-zv))));
  }
}

// ---------------------------------------------------------------------------
extern "C" void kernel_launch(void* const* d_in, const int* in_sizes, int n_in,
                              void* d_out, int out_size, void* d_ws, size_t ws_size,
                              hipStream_t stream){
  (void)in_sizes; (void)n_in; (void)out_size;
  const u16* x = (const u16*)d_in[0];
  u16* outp = (u16*)d_out;

  char* ws = (char*)d_ws;
  size_t off = 0;
  auto alloc = [&](size_t bytes)->void*{
    void* p = (void*)(ws + off);
    off += (bytes + 255) & ~(size_t)255;
    return p;
  };
  int*   cnt   = (int*)  alloc(256);
  u16*   zp    = (u16*)  alloc(512);
  float* stats = (float*)alloc((size_t)3072*4);
  u16*   wc    = (u16*)  alloc((size_t)252288*2);       // small canon tensors
  u16*   Bw1   = (u16*)  alloc((size_t)995328*2);
  u16*   Bw2   = (u16*)  alloc((size_t)995328*2);
  u16*   xc    = (u16*)  alloc((size_t)MTOT*192*2);     // canon x; -> xdb
  u16*   craw  = (u16*)  alloc((size_t)MTOT*192*2);     // conv out; -> xnorm
  u16*   bx    = (u16*)  alloc((size_t)MTOT*192*2);     // x1/xc2; -> hin
  u16*   ubuf  = (u16*)  alloc((size_t)MTOT*384*2);     // u; -> P,Q
  u16*   zbuf  = (u16*)  alloc((size_t)MTOT*384*2);
  u16*   upost = (u16*)  alloc((size_t)MTOT*384*2);     // silu(conv1d); -> yg (in-place safe)
  const size_t NEEDED = off;

  if (ws_size < NEEDED){
    k_diag<<<1,1,0,stream>>>((float*)d_out, (float)(ws_size >> 20));
    return;
  }

  u16* xnorm = craw;
  float* xdb = (float*)xc;
  float* P   = (float*)ubuf;
  float* Q   = (float*)(ubuf + 6291456);   // +12,582,912 bytes
  float* hin = (float*)bx;
  u16*   yg  = upost;

  float* sum1 = stats;        float* sq1 = stats+384;  float* mr1 = stats+768;
  float* sum2 = stats+1536;   float* sq2 = stats+1920; float* mr2 = stats+2304;

  SmallCvt sc;
  const int srcIdx[13] = {2,4,5,6,7,8,9,10,11,12,13,14,15};
  const int ns[13]     = {192,192,192,192,147456,1536,384,16896,4608,384,6144,384,73728};
  const int offs[13]   = {0,192,384,576,768,148224,149760,150144,167040,171648,172032,178176,178560};
  for (int i=0;i<13;i++){ sc.src[i]=d_in[srcIdx[i]]; sc.n[i]=ns[i]; sc.off[i]=offs[i]; }
  const u16 *c1b=wc+0, *c2b=wc+192, *lng=wc+384, *lnb=wc+576, *ipw=wc+768,
            *c1dw=wc+148224, *c1db=wc+149760, *xpw=wc+150144, *dtw=wc+167040,
            *dtb=wc+171648, *alog=wc+172032, *dp=wc+178176, *opw=wc+178560;

  k_init<<<12,256,0,stream>>>(cnt, (float*)zp, stats);
  k_probe<<<1,256,0,stream>>>(x, cnt);
  k_cvt<<<3072,256,0,stream>>>(d_in[0], xc, MTOT*192, cnt);
  k_cvt_small<<<dim3(72,13),256,0,stream>>>(sc, wc, cnt);
  k_wt<<<7776,256,0,stream>>>(d_in[1], d_in[3], Bw1, Bw2, cnt);

  k_conv<<<dim3(256,3),256,0,stream>>>(xc, Bw1, c1b, craw, sum1, sq1);
  k_infin<<<1,384,0,stream>>>(sum1, sq1, mr1);
  k_inapply<<<3072,256,0,stream>>>(craw, mr1, xc, bx, 1);
  k_conv<<<dim3(256,3),256,0,stream>>>(bx, Bw2, c2b, craw, sum2, sq2);
  k_infin<<<1,384,0,stream>>>(sum2, sq2, mr2);
  k_inapply<<<3072,256,0,stream>>>(craw, mr2, xc, bx, 2);

  k_ln<<<dim3(128,2),128,0,stream>>>(bx, lng, lnb, xnorm);
  k_gemm<0><<<dim3(256,12),256,0,stream>>>(xnorm, ipw, 192, 768, ubuf, zbuf, zp, cnt);
  k_conv1d<<<6144,256,0,stream>>>(ubuf, c1dw, c1db, upost);
  k_gemm<1><<<dim3(256,1),256,0,stream>>>(upost, xpw, 384, 44, xdb, nullptr, zp, cnt);
  k_scan1<<<dim3(256,2,2),192,0,stream>>>(xdb, upost, dtw, dtb, alog, P, Q);
  k_scan2<<<48,256,0,stream>>>(P, Q, hin);
  k_scan3<<<dim3(256,2,2),192,0,stream>>>(xdb, upost, zbuf, dtw, dtb, alog, dp, hin, yg);
  k_gemm<2><<<dim3(256,3),256,0,stream>>>(yg, opw, 384, 192, outp, nullptr, zp, cnt);
}

// Round 5
// 597.487 us; speedup vs baseline: 1.6985x; 1.6985x over previous
//
#include <hip/hip_runtime.h>

// ---------------------------------------------------------------------------
// MambaLayer on MI355X (gfx950).
// conv3d -> inorm(+lrelu) -> conv3d -> inorm(+res) -> scrambled reshape + LN
// -> in_proj GEMM -> depthwise conv1d+silu -> x_proj GEMM -> softplus(dt)
// -> chunked selective scan -> gate -> out_proj GEMM.
// Round-5: conv staging via global_load_lds (width=16) — no VGPR prefetch
// (round-4's register prefetch spilled to scratch: 826 MB WRITE_SIZE).
// dw-fused 18-stage K-loop kept (verified correct in round 4).
// A: 130 rows x 13 chunks (stride 104, conflict-free); B: 192 rows x 12
// chunks (stride 96). LDS exactly 64 KiB -> 2 blocks/CU.
// ---------------------------------------------------------------------------

typedef unsigned short u16;
typedef __attribute__((ext_vector_type(8))) short bf16x8;
typedef __attribute__((ext_vector_type(4))) float f4;

#define MTOT 32768

__device__ __forceinline__ float b2f(u16 v){ return __uint_as_float(((unsigned)v)<<16); }
__device__ __forceinline__ u16 f2b(float f){
  unsigned u = __float_as_uint(f);
  return (u16)((u + 0x7fffu + ((u>>16)&1u)) >> 16);      // RNE
}
__device__ __forceinline__ float blo(unsigned v){ return __uint_as_float(v<<16); }
__device__ __forceinline__ float bhi(unsigned v){ return __uint_as_float(v & 0xffff0000u); }
__device__ __forceinline__ unsigned pack2(float a, float b){
  return (unsigned)f2b(a) | ((unsigned)f2b(b)<<16);
}

// async global->LDS, 16 B per lane. LDS dest = wave-uniform base + lane*16;
// passing per-lane base+lane*16 is compatible with that semantics.
__device__ __forceinline__ void gl16(const u16* g, u16* l){
  __builtin_amdgcn_global_load_lds((const __attribute__((address_space(1))) void*)g,
                                   (__attribute__((address_space(3))) void*)l, 16, 0, 0);
}

// --------------------------------------------------------------------- init
__global__ __launch_bounds__(256) void k_init(int* cnt, float* zp, float* stats){
  int i = blockIdx.x*256 + threadIdx.x;
  if (i == 0)   *cnt = 0;
  if (i < 128)  zp[i] = 0.f;
  if (i < 3072) stats[i] = 0.f;
}

__global__ void k_diag(float* o, float v){
  o[0] = v; o[1] = v;
  ((u16*)o)[4] = f2b(v); ((u16*)o)[5] = f2b(v);
}

// --------------------------------------------------------- dtype probe
__global__ __launch_bounds__(256) void k_probe(const u16* __restrict__ x, int* cnt){
  int t = threadIdx.x;
  int c = 0;
  #pragma unroll
  for (int i=0;i<16;i++){
    u16 v = x[t*16 + i];
    if (((v>>7)&0xFF) >= 0x90) c++;
  }
  if (c) atomicAdd(cnt, c);
}

// ----------------------------------------------------- canonical bf16 cvt
__global__ __launch_bounds__(256) void k_cvt(const void* __restrict__ src, u16* __restrict__ dst,
                                             int n, const int* __restrict__ cnt){
  const int gid = blockIdx.x*256 + threadIdx.x;
  if (gid*8 >= n) return;
  if (*cnt > 64){
    const float4* s = (const float4*)src;
    float4 a = s[gid*2], b = s[gid*2+1];
    *(uint4*)(dst + gid*8) = make_uint4(pack2(a.x,a.y), pack2(a.z,a.w),
                                        pack2(b.x,b.y), pack2(b.z,b.w));
  } else {
    ((uint4*)dst)[gid] = ((const uint4*)src)[gid];
  }
}

struct SmallCvt { const void* src[13]; int n[13]; int off[13]; };

__global__ __launch_bounds__(256) void k_cvt_small(SmallCvt sc, u16* __restrict__ wc,
                                                   const int* __restrict__ cnt){
  const int t = blockIdx.y;
  const int gid = blockIdx.x*256 + threadIdx.x;
  const int n = sc.n[t];
  if (gid*8 >= n) return;
  u16* dst = wc + sc.off[t];
  if (*cnt > 64){
    const float4* s = (const float4*)sc.src[t];
    float4 a = s[gid*2], b = s[gid*2+1];
    *(uint4*)(dst + gid*8) = make_uint4(pack2(a.x,a.y), pack2(a.z,a.w),
                                        pack2(b.x,b.y), pack2(b.z,b.w));
  } else {
    *(uint4*)(dst + gid*8) = ((const uint4*)sc.src[t])[gid];
  }
}

// ------------------------------------------------- conv weight permutation
__global__ __launch_bounds__(256) void k_wt(const void* __restrict__ w1, const void* __restrict__ w2,
                                            u16* __restrict__ b1, u16* __restrict__ b2,
                                            const int* __restrict__ cnt){
  int gid = blockIdx.x*256 + threadIdx.x;
  if (gid >= 2*995328) return;
  const bool f32 = *cnt > 64;
  int sel = gid >= 995328 ? 1 : 0;
  int lo  = gid - sel*995328;
  int co = lo / 5184, rr = lo % 5184;
  int p  = rr / 192,  ci = rr % 192;
  const void* s = sel ? w2 : w1;
  const int si = (co*192 + ci)*27 + p;
  u16 v = f32 ? f2b(((const float*)s)[si]) : ((const u16*)s)[si];
  (sel ? b2 : b1)[lo] = v;
}

// ------------------------------------------------------ conv3d shift-GEMM
// M=32768 (b,t,h,w), N=192 (co), K=27 taps x 192 ci. BM=128 BN=64.
// dw-fused: per (dt,dh) stage a 130-row A window + 3 taps of B; 2 K-halves.
// Staging via global_load_lds (DMA, no VGPRs).
__global__ __launch_bounds__(256) void k_conv(const u16* __restrict__ X, const u16* __restrict__ Bw,
                                              const u16* __restrict__ bias, u16* __restrict__ outc,
                                              float* __restrict__ sumG, float* __restrict__ sqG){
  __shared__ u16 Al[1792*8];   // 28,672 B: 130 rows x 13 chunks (stride 104 u16)
  __shared__ u16 Bl[2304*8];   // 36,864 B: 192 rows x 12 chunks (stride 96 u16)
  const int tid = threadIdx.x;
  const int m0 = blockIdx.x*128, n0 = blockIdx.y*64;
  const int bb = blockIdx.x >> 7;
  const int rem0 = m0 & 16383;
  const int t0 = rem0 >> 10, h0 = (rem0 >> 5) & 31;
  const int lane = tid&63, wv = tid>>6, wm = wv>>1, wn = wv&1, lr = lane&15, q = lane>>4;

  // per-thread chunk->global offset tables (chunk id = j*256 + tid)
  int aoff[7];
  #pragma unroll
  for (int j=0;j<7;j++){
    const int c = j*256 + tid;
    const int rw = c/13, cc = c%13;
    aoff[j] = (rw < 130 && cc < 12) ? (rw*192 + cc*8) : 0;   // dummy -> base
  }
  int boff[9];
  #pragma unroll
  for (int j=0;j<9;j++){
    const int c = j*256 + tid;
    const int rw = c/12, cc = c%12;                           // rw = tp*64 + co
    boff[j] = (n0 + (rw & 63))*5184 + (rw >> 6)*192 + cc*8;
  }

  const f4 z4 = {0.f,0.f,0.f,0.f};
  const bf16x8 z8 = {0,0,0,0,0,0,0,0};
  f4 acc[4][2];
  #pragma unroll
  for (int i=0;i<4;i++){
    #pragma unroll
    for (int j=0;j<2;j++) acc[i][j] = z4;
  }

  for (int s=0; s<18; ++s){
    const int dtdh = s>>1, sub = s&1;
    const int dt = dtdh/3 - 1, dh = dtdh%3 - 1;
    __syncthreads();                       // all waves done reading prev stage
    const u16* Ab = X + (ptrdiff_t)(m0 - 1 + dt*1024 + dh*32)*192 + sub*96;
    #pragma unroll
    for (int j=0;j<7;j++) gl16(Ab + aoff[j], Al + (size_t)(j*256 + tid)*8);
    const u16* Bb = Bw + dtdh*576 + sub*96;
    #pragma unroll
    for (int j=0;j<9;j++) gl16(Bb + boff[j], Bl + (size_t)(j*256 + tid)*8);
    __syncthreads();                       // vmcnt drained -> staging visible
    const bool tval = ((unsigned)(t0 + dt) < 16u);
    const bool hv0 = ((unsigned)(h0 + wm*2     + dh) < 32u);  // frags i=0,1
    const bool hv1 = ((unsigned)(h0 + wm*2 + 1 + dh) < 32u);  // frags i=2,3
    if (tval){
      #pragma unroll
      for (int kt=0; kt<3; ++kt){
        bf16x8 bv[3][2];
        #pragma unroll
        for (int tp=0;tp<3;tp++){
          #pragma unroll
          for (int j=0;j<2;j++)
            bv[tp][j] = *(const bf16x8*)&Bl[(tp*64 + wn*32 + j*16 + lr)*96 + kt*32 + q*8];
        }
        #pragma unroll
        for (int i=0;i<4;i++){
          const bool hok = (i<2) ? hv0 : hv1;
          if (!hok) continue;
          const int crow = wm*64 + i*16 + lr;     // central row; w = (i&1)*16+lr
          #pragma unroll
          for (int tp=0;tp<3;tp++){               // dw = tp-1; window row = crow+tp
            bf16x8 av = *(const bf16x8*)&Al[(crow + tp)*104 + kt*32 + q*8];
            if (tp==0 && (i&1)==0) av = (lr==0)  ? z8 : av;   // w=0, dw=-1
            if (tp==2 && (i&1)==1) av = (lr==15) ? z8 : av;   // w=31, dw=+1
            acc[i][0] = __builtin_amdgcn_mfma_f32_16x16x32_bf16(av, bv[tp][0], acc[i][0], 0,0,0);
            acc[i][1] = __builtin_amdgcn_mfma_f32_16x16x32_bf16(av, bv[tp][1], acc[i][1], 0,0,0);
          }
        }
      }
    }
  }

  float psum[2] = {0.f,0.f}, psq[2] = {0.f,0.f};
  #pragma unroll
  for (int j=0;j<2;j++){
    const int col = n0 + wn*32 + j*16 + lr;
    const float bvl = b2f(bias[col]);
    #pragma unroll
    for (int i=0;i<4;i++){
      const int row0 = m0 + wm*64 + i*16 + q*4;
      #pragma unroll
      for (int g=0; g<4; ++g){
        const float v = acc[i][j][g] + bvl;
        outc[(size_t)(row0+g)*192 + col] = f2b(v);
        psum[j] += v; psq[j] += v*v;
      }
    }
  }
  __syncthreads();
  float* red = (float*)Al;
  if (tid < 128) red[tid] = 0.f;
  __syncthreads();
  #pragma unroll
  for (int j=0;j<2;j++){
    const int cl = wn*32 + j*16 + lr;
    atomicAdd(&red[cl], psum[j]);
    atomicAdd(&red[64+cl], psq[j]);
  }
  __syncthreads();
  if (tid < 64){
    atomicAdd(&sumG[bb*192 + n0 + tid], red[tid]);
    atomicAdd(&sqG[bb*192 + n0 + tid], red[64+tid]);
  }
}

// --------------------------------------------------- generic GEMM (B^T in)
template<int EPI>
__global__ __launch_bounds__(256) void k_gemm(const u16* __restrict__ A, const u16* __restrict__ Bm,
                                              const int K, const int NB,
                                              void* __restrict__ o0, void* __restrict__ o1,
                                              const u16* __restrict__ zp,
                                              const int* __restrict__ cnt){
  __shared__ u16 Al[128*104];
  __shared__ u16 Bl[64*104];
  const int tid = threadIdx.x;
  const int m0 = blockIdx.x*128, n0 = blockIdx.y*64;
  const int r = tid>>1, half = tid&1;
  const u16* arow = A + ((size_t)(m0+r)*K + half*48);
  const int bn = tid>>2, bk = tid&3;
  const bool bval = (n0+bn) < NB;
  const u16* brow = Bm + ((size_t)(n0+bn)*K + bk*24);
  const int lane = tid&63, wv = tid>>6, wm = wv>>1, wn = wv&1, lr = lane&15, q = lane>>4;
  const f4 z4 = {0.f,0.f,0.f,0.f};
  f4 acc[4][2];
  #pragma unroll
  for (int i=0;i<4;i++){
    #pragma unroll
    for (int j=0;j<2;j++) acc[i][j] = z4;
  }
  for (int k0=0; k0<K; k0+=96){
    const u16* as = arow + k0;
    const u16* bs = bval ? (brow + k0) : zp;
    __syncthreads();
    #pragma unroll
    for (int i=0;i<6;i++)
      *(uint4*)&Al[r*104 + half*48 + i*8] = *(const uint4*)(as + i*8);
    #pragma unroll
    for (int i=0;i<3;i++)
      *(uint4*)&Bl[bn*104 + bk*24 + i*8] = *(const uint4*)(bs + i*8);
    __syncthreads();
    #pragma unroll
    for (int kt=0; kt<3; ++kt){
      bf16x8 av[4], bv[2];
      #pragma unroll
      for (int i=0;i<4;i++) av[i] = *(const bf16x8*)&Al[(wm*64 + i*16 + lr)*104 + kt*32 + q*8];
      #pragma unroll
      for (int j=0;j<2;j++) bv[j] = *(const bf16x8*)&Bl[(wn*32 + j*16 + lr)*104 + kt*32 + q*8];
      #pragma unroll
      for (int i=0;i<4;i++){
        #pragma unroll
        for (int j=0;j<2;j++)
          acc[i][j] = __builtin_amdgcn_mfma_f32_16x16x32_bf16(av[i], bv[j], acc[i][j], 0,0,0);
      }
    }
  }
  const bool f32o = (EPI == 2) && (*cnt > 64);
  #pragma unroll
  for (int j=0;j<2;j++){
    const int col = n0 + wn*32 + j*16 + lr;
    #pragma unroll
    for (int i=0;i<4;i++){
      const int row0 = m0 + wm*64 + i*16 + q*4;
      #pragma unroll
      for (int g=0; g<4; ++g){
        const int row = row0 + g;
        const float v = acc[i][j][g];
        if (EPI == 0){
          if (col < 384) ((u16*)o0)[(size_t)row*384 + col] = f2b(v);
          else           ((u16*)o1)[(size_t)row*384 + (col-384)] = f2b(v);
        } else if (EPI == 1){
          if (col < 44)  ((float*)o0)[(size_t)row*44 + col] = v;
        } else {
          if (f32o) ((float*)o0)[(size_t)row*192 + col] = v;
          else      ((u16*) o0)[(size_t)row*192 + col] = f2b(v);
        }
      }
    }
  }
}

// ----------------------------------------------------- instance norm final
__global__ __launch_bounds__(384) void k_infin(const float* __restrict__ s, const float* __restrict__ s2,
                                               float* __restrict__ mr){
  const int i = threadIdx.x;
  const float mean = s[i]*(1.f/16384.f);
  const float var  = s2[i]*(1.f/16384.f) - mean*mean;
  mr[i]     = mean;
  mr[384+i] = rsqrtf(var + 1e-5f);
}

// mode 1: lrelu(norm) -> bf16 ; mode 2: norm + residual(bf16) -> bf16
__global__ __launch_bounds__(256) void k_inapply(const u16* __restrict__ craw, const float* __restrict__ mr,
                                                 const u16* __restrict__ resid, u16* __restrict__ outp,
                                                 const int mode){
  const int gid = blockIdx.x*256 + threadIdx.x;
  const size_t base = (size_t)gid*8;
  const int mrow = gid/24;
  const int c0 = (gid%24)*8;
  const int b = mrow >> 14;
  const uint4 rv = *(const uint4*)(craw + base);
  float vv[8] = {blo(rv.x),bhi(rv.x),blo(rv.y),bhi(rv.y),blo(rv.z),bhi(rv.z),blo(rv.w),bhi(rv.w)};
  uint4 xv;
  float rr[8];
  if (mode == 2){
    xv = *(const uint4*)(resid + base);
    rr[0]=blo(xv.x); rr[1]=bhi(xv.x); rr[2]=blo(xv.y); rr[3]=bhi(xv.y);
    rr[4]=blo(xv.z); rr[5]=bhi(xv.z); rr[6]=blo(xv.w); rr[7]=bhi(xv.w);
  }
  unsigned pk[4];
  #pragma unroll
  for (int k2=0;k2<4;k2++){
    const int c = c0 + 2*k2;
    float a0 = (vv[2*k2]   - mr[b*192+c])  * mr[384 + b*192 + c];
    float a1 = (vv[2*k2+1] - mr[b*192+c+1])* mr[384 + b*192 + c+1];
    if (mode == 1){ a0 = a0 > 0.f ? a0 : 0.01f*a0; a1 = a1 > 0.f ? a1 : 0.01f*a1; }
    else          { a0 += rr[2*k2]; a1 += rr[2*k2+1]; }
    pk[k2] = pack2(a0, a1);
  }
  *(uint4*)(outp + base) = make_uint4(pk[0],pk[1],pk[2],pk[3]);
}

// ------------------------------------- scrambled reshape + LayerNorm(192)
__global__ __launch_bounds__(128) void k_ln(const u16* __restrict__ F, const u16* __restrict__ g,
                                            const u16* __restrict__ bb, u16* __restrict__ xn){
  __shared__ u16 S[192*128];
  const int tid = threadIdx.x;
  const int b = blockIdx.y;
  const int l0 = blockIdx.x*128;
  const u16* Fb = F + (size_t)b*3145728;
  for (int qi = tid; qi < 3072; qi += 128){
    int c = qi >> 4, o = (qi & 15)*8;
    *(uint4*)&S[c*128 + o] = *(const uint4*)(Fb + (size_t)c*16384 + l0 + o);
  }
  __syncthreads();
  float sum = 0.f, sq = 0.f;
  for (int c=0;c<192;c++){ float v = b2f(S[c*128 + tid]); sum += v; sq += v*v; }
  const float mean = sum*(1.f/192.f);
  const float rs = rsqrtf(sq*(1.f/192.f) - mean*mean + 1e-5f);
  u16* dst = xn + ((size_t)(b*16384 + l0 + tid))*192;
  for (int c0=0;c0<192;c0+=8){
    unsigned pk[4];
    #pragma unroll
    for (int k2=0;k2<4;k2++){
      int c = c0 + 2*k2;
      float v0 = (b2f(S[(c  )*128+tid]) - mean)*rs*b2f(g[c  ]) + b2f(bb[c  ]);
      float v1 = (b2f(S[(c+1)*128+tid]) - mean)*rs*b2f(g[c+1]) + b2f(bb[c+1]);
      pk[k2] = pack2(v0, v1);
    }
    *(uint4*)(dst + c0) = make_uint4(pk[0],pk[1],pk[2],pk[3]);
  }
}

// ----------------------------------- causal depthwise conv1d (w=4) + silu
__global__ __launch_bounds__(256) void k_conv1d(const u16* __restrict__ u, const u16* __restrict__ w,
                                                const u16* __restrict__ bias, u16* __restrict__ up){
  const int gid = blockIdx.x*256 + threadIdx.x;
  const int mrow = gid/48, d8 = (gid%48)*8;
  const int l = mrow & 16383;
  float acc[8];
  #pragma unroll
  for (int k=0;k<8;k++) acc[k] = b2f(bias[d8+k]);
  float wk[4][8];
  #pragma unroll
  for (int dd=0;dd<8;dd++){
    uint2 tw = *(const uint2*)(w + (size_t)(d8+dd)*4);
    wk[0][dd]=blo(tw.x); wk[1][dd]=bhi(tw.x); wk[2][dd]=blo(tw.y); wk[3][dd]=bhi(tw.y);
  }
  #pragma unroll
  for (int k=0;k<4;k++){
    if (l - 3 + k < 0) continue;
    uint4 tv = *(const uint4*)(u + ((size_t)(mrow-3+k))*384 + d8);
    float uv[8] = {blo(tv.x),bhi(tv.x),blo(tv.y),bhi(tv.y),blo(tv.z),bhi(tv.z),blo(tv.w),bhi(tv.w)};
    #pragma unroll
    for (int dd=0;dd<8;dd++) acc[dd] += uv[dd]*wk[k][dd];
  }
  unsigned pk[4];
  #pragma unroll
  for (int k2=0;k2<4;k2++){
    float a0 = acc[2*k2], a1 = acc[2*k2+1];
    a0 = a0/(1.f + __expf(-a0));
    a1 = a1/(1.f + __expf(-a1));
    pk[k2] = pack2(a0, a1);
  }
  *(uint4*)(up + (size_t)mrow*384 + d8) = make_uint4(pk[0],pk[1],pk[2],pk[3]);
}

// --------------------------------------------- selective scan, chunked
// thread-per-d, 16 states in registers. 256 chunks x 64 steps.
__global__ __launch_bounds__(192) void k_scan1(const float* __restrict__ xdb, const u16* __restrict__ up,
                                               const u16* __restrict__ dtw, const u16* __restrict__ dtb,
                                               const u16* __restrict__ alog,
                                               float* __restrict__ P, float* __restrict__ Q){
  __shared__ float xdbS[64*44];
  const int tid = threadIdx.x;
  const int chunk = blockIdx.x, b = blockIdx.y;
  const int d = blockIdx.z*192 + tid;
  const size_t mbase = (size_t)b*16384 + chunk*64;
  const float* xs = xdb + mbase*44;
  for (int qi=tid; qi<704; qi+=192)
    *(float4*)&xdbS[qi*4] = *(const float4*)(xs + (size_t)qi*4);
  float w[12];
  #pragma unroll
  for (int i=0;i<12;i++) w[i] = b2f(dtw[d*12+i]);
  const float dtbv = b2f(dtb[d]);
  float Av[16];
  #pragma unroll
  for (int s=0;s<16;s++) Av[s] = -__expf(b2f(alog[d*16+s]));
  float pp[16], qq[16];
  #pragma unroll
  for (int s=0;s<16;s++){ pp[s]=1.f; qq[s]=0.f; }
  const u16* uptr = up + mbase*384 + d;
  __syncthreads();
  for (int l=0;l<64;l++){
    const float* row = &xdbS[l*44];
    const float4 r0 = *(const float4*)(row);
    const float4 r1 = *(const float4*)(row+4);
    const float4 r2 = *(const float4*)(row+8);
    float a = dtbv + r0.x*w[0]+r0.y*w[1]+r0.z*w[2]+r0.w*w[3]
                   + r1.x*w[4]+r1.y*w[5]+r1.z*w[6]+r1.w*w[7]
                   + r2.x*w[8]+r2.y*w[9]+r2.z*w[10]+r2.w*w[11];
    const float dl = a > 20.f ? a : __logf(1.f + __expf(a));
    const float uv = b2f(uptr[(size_t)l*384]);
    const float dlu = dl*uv;
    const float4 B0 = *(const float4*)(row+12);
    const float4 B1 = *(const float4*)(row+16);
    const float4 B2 = *(const float4*)(row+20);
    const float4 B3 = *(const float4*)(row+24);
    const float Bv[16] = {B0.x,B0.y,B0.z,B0.w,B1.x,B1.y,B1.z,B1.w,
                          B2.x,B2.y,B2.z,B2.w,B3.x,B3.y,B3.z,B3.w};
    #pragma unroll
    for (int s=0;s<16;s++){
      const float as = __expf(dl*Av[s]);
      pp[s] *= as;
      qq[s] = as*qq[s] + dlu*Bv[s];
    }
  }
  const size_t o = (((size_t)b*256 + chunk)*384 + d)*16;
  float* Po = P + o; float* Qo = Q + o;
  *(float4*)(Po+ 0) = make_float4(pp[0],pp[1],pp[2],pp[3]);
  *(float4*)(Po+ 4) = make_float4(pp[4],pp[5],pp[6],pp[7]);
  *(float4*)(Po+ 8) = make_float4(pp[8],pp[9],pp[10],pp[11]);
  *(float4*)(Po+12) = make_float4(pp[12],pp[13],pp[14],pp[15]);
  *(float4*)(Qo+ 0) = make_float4(qq[0],qq[1],qq[2],qq[3]);
  *(float4*)(Qo+ 4) = make_float4(qq[4],qq[5],qq[6],qq[7]);
  *(float4*)(Qo+ 8) = make_float4(qq[8],qq[9],qq[10],qq[11]);
  *(float4*)(Qo+12) = make_float4(qq[12],qq[13],qq[14],qq[15]);
}

__global__ __launch_bounds__(256) void k_scan2(const float* __restrict__ P, const float* __restrict__ Q,
                                               float* __restrict__ hin){
  const int gid = blockIdx.x*256 + threadIdx.x;      // 12288
  const int b = gid / 6144, ds = gid % 6144;
  const size_t base = (size_t)b*1572864 + ds;
  float h = 0.f;
  for (int g2=0; g2<256; ++g2){
    const size_t idx = base + (size_t)g2*6144;
    hin[idx] = h;
    h = P[idx]*h + Q[idx];
  }
}

__global__ __launch_bounds__(192) void k_scan3(const float* __restrict__ xdb, const u16* __restrict__ up,
                                               const u16* __restrict__ zb,
                                               const u16* __restrict__ dtw, const u16* __restrict__ dtb,
                                               const u16* __restrict__ alog, const u16* __restrict__ dp,
                                               const float* __restrict__ hin, u16* __restrict__ yg){
  __shared__ float xdbS[64*44];
  const int tid = threadIdx.x;
  const int chunk = blockIdx.x, b = blockIdx.y;
  const int d = blockIdx.z*192 + tid;
  const size_t mbase = (size_t)b*16384 + chunk*64;
  const float* xs = xdb + mbase*44;
  for (int qi=tid; qi<704; qi+=192)
    *(float4*)&xdbS[qi*4] = *(const float4*)(xs + (size_t)qi*4);
  float w[12];
  #pragma unroll
  for (int i=0;i<12;i++) w[i] = b2f(dtw[d*12+i]);
  const float dtbv = b2f(dtb[d]);
  float Av[16];
  #pragma unroll
  for (int s=0;s<16;s++) Av[s] = -__expf(b2f(alog[d*16+s]));
  const float Dv = b2f(dp[d]);
  float h[16];
  {
    const float* hi = hin + (((size_t)b*256 + chunk)*384 + d)*16;
    const float4 h0 = *(const float4*)(hi+0);
    const float4 h1 = *(const float4*)(hi+4);
    const float4 h2 = *(const float4*)(hi+8);
    const float4 h3 = *(const float4*)(hi+12);
    h[0]=h0.x;h[1]=h0.y;h[2]=h0.z;h[3]=h0.w;
    h[4]=h1.x;h[5]=h1.y;h[6]=h1.z;h[7]=h1.w;
    h[8]=h2.x;h[9]=h2.y;h[10]=h2.z;h[11]=h2.w;
    h[12]=h3.x;h[13]=h3.y;h[14]=h3.z;h[15]=h3.w;
  }
  const u16* uptr = up + mbase*384 + d;
  const u16* zptr = zb + mbase*384 + d;
  u16* yptr = yg + mbase*384 + d;
  __syncthreads();
  for (int l=0;l<64;l++){
    const float* row = &xdbS[l*44];
    const float4 r0 = *(const float4*)(row);
    const float4 r1 = *(const float4*)(row+4);
    const float4 r2 = *(const float4*)(row+8);
    float a = dtbv + r0.x*w[0]+r0.y*w[1]+r0.z*w[2]+r0.w*w[3]
                   + r1.x*w[4]+r1.y*w[5]+r1.z*w[6]+r1.w*w[7]
                   + r2.x*w[8]+r2.y*w[9]+r2.z*w[10]+r2.w*w[11];
    const float dl = a > 20.f ? a : __logf(1.f + __expf(a));
    const float uv = b2f(uptr[(size_t)l*384]);
    const float dlu = dl*uv;
    const float4 B0 = *(const float4*)(row+12);
    const float4 B1 = *(const float4*)(row+16);
    const float4 B2 = *(const float4*)(row+20);
    const float4 B3 = *(const float4*)(row+24);
    const float4 C0 = *(const float4*)(row+28);
    const float4 C1 = *(const float4*)(row+32);
    const float4 C2 = *(const float4*)(row+36);
    const float4 C3 = *(const float4*)(row+40);
    const float Bv[16] = {B0.x,B0.y,B0.z,B0.w,B1.x,B1.y,B1.z,B1.w,
                          B2.x,B2.y,B2.z,B2.w,B3.x,B3.y,B3.z,B3.w};
    const float Cv[16] = {C0.x,C0.y,C0.z,C0.w,C1.x,C1.y,C1.z,C1.w,
                          C2.x,C2.y,C2.z,C2.w,C3.x,C3.y,C3.z,C3.w};
    float ct = 0.f;
    #pragma unroll
    for (int s=0;s<16;s++){
      const float as = __expf(dl*Av[s]);
      h[s] = as*h[s] + dlu*Bv[s];
      ct += h[s]*Cv[s];
    }
    const float yv = ct + uv*Dv;
    const float zv = b2f(zptr[(size_t)l*384]);
    yptr[(size_t)l*384] = f2b(yv * (zv/(1.f + __expf(-zv))));
  }
}

// ---------------------------------------------------------------------------
extern "C" void kernel_launch(void* const* d_in, const int* in_sizes, int n_in,
                              void* d_out, int out_size, void* d_ws, size_t ws_size,
                              hipStream_t stream){
  (void)in_sizes; (void)n_in; (void)out_size;
  const u16* x = (const u16*)d_in[0];
  u16* outp = (u16*)d_out;

  char* ws = (char*)d_ws;
  size_t off = 0;
  auto alloc = [&](size_t bytes)->void*{
    void* p = (void*)(ws + off);
    off += (bytes + 255) & ~(size_t)255;
    return p;
  };
  int*   cnt   = (int*)  alloc(256);
  u16*   zp    = (u16*)  alloc(512);
  float* stats = (float*)alloc((size_t)3072*4);
  u16*   wc    = (u16*)  alloc((size_t)252288*2);       // small canon tensors
  u16*   Bw1   = (u16*)  alloc((size_t)995328*2);
  u16*   Bw2   = (u16*)  alloc((size_t)995328*2);
  u16*   xc    = (u16*)  alloc((size_t)MTOT*192*2);     // canon x; -> xdb
  u16*   craw  = (u16*)  alloc((size_t)MTOT*192*2);     // conv out; -> xnorm
  u16*   bx    = (u16*)  alloc((size_t)MTOT*192*2);     // x1/xc2; -> hin
  u16*   ubuf  = (u16*)  alloc((size_t)MTOT*384*2);     // u; -> P,Q
  u16*   zbuf  = (u16*)  alloc((size_t)MTOT*384*2);
  u16*   upost = (u16*)  alloc((size_t)MTOT*384*2);     // silu(conv1d); -> yg (in-place safe)
  const size_t NEEDED = off;

  if (ws_size < NEEDED){
    k_diag<<<1,1,0,stream>>>((float*)d_out, (float)(ws_size >> 20));
    return;
  }

  u16* xnorm = craw;
  float* xdb = (float*)xc;
  float* P   = (float*)ubuf;
  float* Q   = (float*)(ubuf + 6291456);   // +12,582,912 bytes
  float* hin = (float*)bx;
  u16*   yg  = upost;

  float* sum1 = stats;        float* sq1 = stats+384;  float* mr1 = stats+768;
  float* sum2 = stats+1536;   float* sq2 = stats+1920; float* mr2 = stats+2304;

  SmallCvt sc;
  const int srcIdx[13] = {2,4,5,6,7,8,9,10,11,12,13,14,15};
  const int ns[13]     = {192,192,192,192,147456,1536,384,16896,4608,384,6144,384,73728};
  const int offs[13]   = {0,192,384,576,768,148224,149760,150144,167040,171648,172032,178176,178560};
  for (int i=0;i<13;i++){ sc.src[i]=d_in[srcIdx[i]]; sc.n[i]=ns[i]; sc.off[i]=offs[i]; }
  const u16 *c1b=wc+0, *c2b=wc+192, *lng=wc+384, *lnb=wc+576, *ipw=wc+768,
            *c1dw=wc+148224, *c1db=wc+149760, *xpw=wc+150144, *dtw=wc+167040,
            *dtb=wc+171648, *alog=wc+172032, *dp=wc+178176, *opw=wc+178560;

  k_init<<<12,256,0,stream>>>(cnt, (float*)zp, stats);
  k_probe<<<1,256,0,stream>>>(x, cnt);
  k_cvt<<<3072,256,0,stream>>>(d_in[0], xc, MTOT*192, cnt);
  k_cvt_small<<<dim3(72,13),256,0,stream>>>(sc, wc, cnt);
  k_wt<<<7776,256,0,stream>>>(d_in[1], d_in[3], Bw1, Bw2, cnt);

  k_conv<<<dim3(256,3),256,0,stream>>>(xc, Bw1, c1b, craw, sum1, sq1);
  k_infin<<<1,384,0,stream>>>(sum1, sq1, mr1);
  k_inapply<<<3072,256,0,stream>>>(craw, mr1, xc, bx, 1);
  k_conv<<<dim3(256,3),256,0,stream>>>(bx, Bw2, c2b, craw, sum2, sq2);
  k_infin<<<1,384,0,stream>>>(sum2, sq2, mr2);
  k_inapply<<<3072,256,0,stream>>>(craw, mr2, xc, bx, 2);

  k_ln<<<dim3(128,2),128,0,stream>>>(bx, lng, lnb, xnorm);
  k_gemm<0><<<dim3(256,12),256,0,stream>>>(xnorm, ipw, 192, 768, ubuf, zbuf, zp, cnt);
  k_conv1d<<<6144,256,0,stream>>>(ubuf, c1dw, c1db, upost);
  k_gemm<1><<<dim3(256,1),256,0,stream>>>(upost, xpw, 384, 44, xdb, nullptr, zp, cnt);
  k_scan1<<<dim3(256,2,2),192,0,stream>>>(xdb, upost, dtw, dtb, alog, P, Q);
  k_scan2<<<48,256,0,stream>>>(P, Q, hin);
  k_scan3<<<dim3(256,2,2),192,0,stream>>>(xdb, upost, zbuf, dtw, dtb, alog, dp, hin, yg);
  k_gemm<2><<<dim3(256,3),256,0,stream>>>(yg, opw, 384, 192, outp, nullptr, zp, cnt);
}

// Round 7
// 555.130 us; speedup vs baseline: 1.8281x; 1.0763x over previous
//
#include <hip/hip_runtime.h>

// ---------------------------------------------------------------------------
// MambaLayer on MI355X (gfx950).
// conv3d -> inorm(+lrelu) -> conv3d -> inorm(+res) -> scrambled reshape + LN
// -> in_proj GEMM -> depthwise conv1d+silu -> x_proj GEMM -> softplus(dt)
// -> chunked selective scan -> gate -> out_proj GEMM.
// Round-7: round-6's K=64/27-stage conv re-tile with two bugs fixed:
// (a) aoff double-subtract (rw-1 -> rw; Ab already at m0-1);
// (b) no exec-masked global_load_lds (per-lane predicates shift the wave-
//     uniform LDS base) — all lanes always issue; pad chunks read offset 0
//     and land in never-read LDS slots. LDS 48 KiB -> 3 blocks/CU.
// ---------------------------------------------------------------------------

typedef unsigned short u16;
typedef __attribute__((ext_vector_type(8))) short bf16x8;
typedef __attribute__((ext_vector_type(4))) float f4;

#define MTOT 32768

__device__ __forceinline__ float b2f(u16 v){ return __uint_as_float(((unsigned)v)<<16); }
__device__ __forceinline__ u16 f2b(float f){
  unsigned u = __float_as_uint(f);
  return (u16)((u + 0x7fffu + ((u>>16)&1u)) >> 16);      // RNE
}
__device__ __forceinline__ float blo(unsigned v){ return __uint_as_float(v<<16); }
__device__ __forceinline__ float bhi(unsigned v){ return __uint_as_float(v & 0xffff0000u); }
__device__ __forceinline__ unsigned pack2(float a, float b){
  return (unsigned)f2b(a) | ((unsigned)f2b(b)<<16);
}

// async global->LDS, 16 B per lane. Must be issued by ALL lanes of the wave
// with lane-linear LDS pointers (wave-uniform base + lane*16 semantics).
__device__ __forceinline__ void gl16(const u16* g, u16* l){
  __builtin_amdgcn_global_load_lds((const __attribute__((address_space(1))) void*)g,
                                   (__attribute__((address_space(3))) void*)l, 16, 0, 0);
}

// --------------------------------------------------------------------- init
__global__ __launch_bounds__(256) void k_init(int* cnt, float* zp, float* stats){
  int i = blockIdx.x*256 + threadIdx.x;
  if (i == 0)   *cnt = 0;
  if (i < 128)  zp[i] = 0.f;
  if (i < 3072) stats[i] = 0.f;
}

__global__ void k_diag(float* o, float v){
  o[0] = v; o[1] = v;
  ((u16*)o)[4] = f2b(v); ((u16*)o)[5] = f2b(v);
}

// --------------------------------------------------------- dtype probe
__global__ __launch_bounds__(256) void k_probe(const u16* __restrict__ x, int* cnt){
  int t = threadIdx.x;
  int c = 0;
  #pragma unroll
  for (int i=0;i<16;i++){
    u16 v = x[t*16 + i];
    if (((v>>7)&0xFF) >= 0x90) c++;
  }
  if (c) atomicAdd(cnt, c);
}

// ----------------------------------------------------- canonical bf16 cvt
__global__ __launch_bounds__(256) void k_cvt(const void* __restrict__ src, u16* __restrict__ dst,
                                             int n, const int* __restrict__ cnt){
  const int gid = blockIdx.x*256 + threadIdx.x;
  if (gid*8 >= n) return;
  if (*cnt > 64){
    const float4* s = (const float4*)src;
    float4 a = s[gid*2], b = s[gid*2+1];
    *(uint4*)(dst + gid*8) = make_uint4(pack2(a.x,a.y), pack2(a.z,a.w),
                                        pack2(b.x,b.y), pack2(b.z,b.w));
  } else {
    ((uint4*)dst)[gid] = ((const uint4*)src)[gid];
  }
}

struct SmallCvt { const void* src[13]; int n[13]; int off[13]; };

__global__ __launch_bounds__(256) void k_cvt_small(SmallCvt sc, u16* __restrict__ wc,
                                                   const int* __restrict__ cnt){
  const int t = blockIdx.y;
  const int gid = blockIdx.x*256 + threadIdx.x;
  const int n = sc.n[t];
  if (gid*8 >= n) return;
  u16* dst = wc + sc.off[t];
  if (*cnt > 64){
    const float4* s = (const float4*)sc.src[t];
    float4 a = s[gid*2], b = s[gid*2+1];
    *(uint4*)(dst + gid*8) = make_uint4(pack2(a.x,a.y), pack2(a.z,a.w),
                                        pack2(b.x,b.y), pack2(b.z,b.w));
  } else {
    *(uint4*)(dst + gid*8) = ((const uint4*)sc.src[t])[gid];
  }
}

// ------------------------------------------------- conv weight permutation
__global__ __launch_bounds__(256) void k_wt(const void* __restrict__ w1, const void* __restrict__ w2,
                                            u16* __restrict__ b1, u16* __restrict__ b2,
                                            const int* __restrict__ cnt){
  int gid = blockIdx.x*256 + threadIdx.x;
  if (gid >= 2*995328) return;
  const bool f32 = *cnt > 64;
  int sel = gid >= 995328 ? 1 : 0;
  int lo  = gid - sel*995328;
  int co = lo / 5184, rr = lo % 5184;
  int p  = rr / 192,  ci = rr % 192;
  const void* s = sel ? w2 : w1;
  const int si = (co*192 + ci)*27 + p;
  u16 v = f32 ? f2b(((const float*)s)[si]) : ((const u16*)s)[si];
  (sel ? b2 : b1)[lo] = v;
}

// ------------------------------------------------------ conv3d shift-GEMM
// M=32768 (b,t,h,w), N=192 (co), K=27 taps x 192 ci. BM=128 BN=64.
// dw-fused; 27 stages of (dt,dh) x K-64-third. LDS row stride 72 u16
// (36 dw = 4 mod 32 -> conflict-free fragment reads).
__global__ __launch_bounds__(256) void k_conv(const u16* __restrict__ X, const u16* __restrict__ Bw,
                                              const u16* __restrict__ bias, u16* __restrict__ outc,
                                              float* __restrict__ sumG, float* __restrict__ sqG){
  __shared__ u16 Al[1280*8];   // 20,480 B: 130 rows x (8 data + 1 pad) chunks; slots for 5*256 chunks
  __shared__ u16 Bl[1792*8];   // 28,672 B: 192 rows x 9 chunks; slots for 7*256 chunks
  const int tid = threadIdx.x;
  const int m0 = blockIdx.x*128, n0 = blockIdx.y*64;
  const int bb = blockIdx.x >> 7;
  const int rem0 = m0 & 16383;
  const int t0 = rem0 >> 10, h0 = (rem0 >> 5) & 31;
  const int lane = tid&63, wv = tid>>6, wm = wv>>1, wn = wv&1, lr = lane&15, q = lane>>4;

  // chunk tables: chunk id c = j*256+tid; 9 chunks/row (8 data + 1 pad).
  // Window row rw maps to global row m0-1+rw (Ab already holds the -1).
  int aoff[5];
  #pragma unroll
  for (int j=0;j<5;j++){
    const int c = j*256 + tid;
    const int rw = c/9, cc = c%9;
    aoff[j] = (c < 1170 && cc < 8) ? (rw*192 + cc*8) : 0;   // pad/overflow -> base
  }
  int boff[7];
  #pragma unroll
  for (int j=0;j<7;j++){
    const int c = j*256 + tid;
    const int rw = c/9, cc = c%9;                 // rw = tp*64 + co
    boff[j] = (c < 1728 && cc < 8) ? ((n0 + (rw & 63))*5184 + (rw >> 6)*192 + cc*8) : 0;
  }

  const f4 z4 = {0.f,0.f,0.f,0.f};
  const bf16x8 z8 = {0,0,0,0,0,0,0,0};
  f4 acc[4][2];
  #pragma unroll
  for (int i=0;i<4;i++){
    #pragma unroll
    for (int j=0;j<2;j++) acc[i][j] = z4;
  }

  for (int s=0; s<27; ++s){
    const int dtdh = s/3, sub = s - dtdh*3;
    const int dt = dtdh/3 - 1, dh = dtdh%3 - 1;
    __syncthreads();                       // all waves done reading prev stage
    const u16* Ab = X + (ptrdiff_t)(m0 - 1 + dt*1024 + dh*32)*192 + sub*64;
    #pragma unroll
    for (int j=0;j<5;j++) gl16(Ab + aoff[j], Al + (size_t)(j*256 + tid)*8);
    const u16* Bb = Bw + dtdh*576 + sub*64;
    #pragma unroll
    for (int j=0;j<7;j++) gl16(Bb + boff[j], Bl + (size_t)(j*256 + tid)*8);
    __syncthreads();                       // DMA drained -> staging visible
    const bool tval = ((unsigned)(t0 + dt) < 16u);
    const bool hv0 = ((unsigned)(h0 + wm*2     + dh) < 32u);  // frags i=0,1
    const bool hv1 = ((unsigned)(h0 + wm*2 + 1 + dh) < 32u);  // frags i=2,3
    if (tval){
      #pragma unroll
      for (int kt=0; kt<2; ++kt){
        bf16x8 bv[3][2];
        #pragma unroll
        for (int tp=0;tp<3;tp++){
          #pragma unroll
          for (int j=0;j<2;j++)
            bv[tp][j] = *(const bf16x8*)&Bl[(tp*64 + wn*32 + j*16 + lr)*72 + kt*32 + q*8];
        }
        #pragma unroll
        for (int i=0;i<4;i++){
          const bool hok = (i<2) ? hv0 : hv1;
          if (!hok) continue;
          const int crow = wm*64 + i*16 + lr;     // central row; w = (i&1)*16+lr
          #pragma unroll
          for (int tp=0;tp<3;tp++){               // dw = tp-1; window row = crow+tp
            bf16x8 av = *(const bf16x8*)&Al[(crow + tp)*72 + kt*32 + q*8];
            if (tp==0 && (i&1)==0) av = (lr==0)  ? z8 : av;   // w=0, dw=-1
            if (tp==2 && (i&1)==1) av = (lr==15) ? z8 : av;   // w=31, dw=+1
            acc[i][0] = __builtin_amdgcn_mfma_f32_16x16x32_bf16(av, bv[tp][0], acc[i][0], 0,0,0);
            acc[i][1] = __builtin_amdgcn_mfma_f32_16x16x32_bf16(av, bv[tp][1], acc[i][1], 0,0,0);
          }
        }
      }
    }
  }

  float psum[2] = {0.f,0.f}, psq[2] = {0.f,0.f};
  #pragma unroll
  for (int j=0;j<2;j++){
    const int col = n0 + wn*32 + j*16 + lr;
    const float bvl = b2f(bias[col]);
    #pragma unroll
    for (int i=0;i<4;i++){
      const int row0 = m0 + wm*64 + i*16 + q*4;
      #pragma unroll
      for (int g=0; g<4; ++g){
        const float v = acc[i][j][g] + bvl;
        outc[(size_t)(row0+g)*192 + col] = f2b(v);
        psum[j] += v; psq[j] += v*v;
      }
    }
  }
  __syncthreads();
  float* red = (float*)Al;
  if (tid < 128) red[tid] = 0.f;
  __syncthreads();
  #pragma unroll
  for (int j=0;j<2;j++){
    const int cl = wn*32 + j*16 + lr;
    atomicAdd(&red[cl], psum[j]);
    atomicAdd(&red[64+cl], psq[j]);
  }
  __syncthreads();
  if (tid < 64){
    atomicAdd(&sumG[bb*192 + n0 + tid], red[tid]);
    atomicAdd(&sqG[bb*192 + n0 + tid], red[64+tid]);
  }
}

// --------------------------------------------------- generic GEMM (B^T in)
template<int EPI>
__global__ __launch_bounds__(256) void k_gemm(const u16* __restrict__ A, const u16* __restrict__ Bm,
                                              const int K, const int NB,
                                              void* __restrict__ o0, void* __restrict__ o1,
                                              const u16* __restrict__ zp,
                                              const int* __restrict__ cnt){
  __shared__ u16 Al[128*104];
  __shared__ u16 Bl[64*104];
  const int tid = threadIdx.x;
  const int m0 = blockIdx.x*128, n0 = blockIdx.y*64;
  const int r = tid>>1, half = tid&1;
  const u16* arow = A + ((size_t)(m0+r)*K + half*48);
  const int bn = tid>>2, bk = tid&3;
  const bool bval = (n0+bn) < NB;
  const u16* brow = Bm + ((size_t)(n0+bn)*K + bk*24);
  const int lane = tid&63, wv = tid>>6, wm = wv>>1, wn = wv&1, lr = lane&15, q = lane>>4;
  const f4 z4 = {0.f,0.f,0.f,0.f};
  f4 acc[4][2];
  #pragma unroll
  for (int i=0;i<4;i++){
    #pragma unroll
    for (int j=0;j<2;j++) acc[i][j] = z4;
  }
  for (int k0=0; k0<K; k0+=96){
    const u16* as = arow + k0;
    const u16* bs = bval ? (brow + k0) : zp;
    __syncthreads();
    #pragma unroll
    for (int i=0;i<6;i++)
      *(uint4*)&Al[r*104 + half*48 + i*8] = *(const uint4*)(as + i*8);
    #pragma unroll
    for (int i=0;i<3;i++)
      *(uint4*)&Bl[bn*104 + bk*24 + i*8] = *(const uint4*)(bs + i*8);
    __syncthreads();
    #pragma unroll
    for (int kt=0; kt<3; ++kt){
      bf16x8 av[4], bv[2];
      #pragma unroll
      for (int i=0;i<4;i++) av[i] = *(const bf16x8*)&Al[(wm*64 + i*16 + lr)*104 + kt*32 + q*8];
      #pragma unroll
      for (int j=0;j<2;j++) bv[j] = *(const bf16x8*)&Bl[(wn*32 + j*16 + lr)*104 + kt*32 + q*8];
      #pragma unroll
      for (int i=0;i<4;i++){
        #pragma unroll
        for (int j=0;j<2;j++)
          acc[i][j] = __builtin_amdgcn_mfma_f32_16x16x32_bf16(av[i], bv[j], acc[i][j], 0,0,0);
      }
    }
  }
  const bool f32o = (EPI == 2) && (*cnt > 64);
  #pragma unroll
  for (int j=0;j<2;j++){
    const int col = n0 + wn*32 + j*16 + lr;
    #pragma unroll
    for (int i=0;i<4;i++){
      const int row0 = m0 + wm*64 + i*16 + q*4;
      #pragma unroll
      for (int g=0; g<4; ++g){
        const int row = row0 + g;
        const float v = acc[i][j][g];
        if (EPI == 0){
          if (col < 384) ((u16*)o0)[(size_t)row*384 + col] = f2b(v);
          else           ((u16*)o1)[(size_t)row*384 + (col-384)] = f2b(v);
        } else if (EPI == 1){
          if (col < 44)  ((float*)o0)[(size_t)row*44 + col] = v;
        } else {
          if (f32o) ((float*)o0)[(size_t)row*192 + col] = v;
          else      ((u16*) o0)[(size_t)row*192 + col] = f2b(v);
        }
      }
    }
  }
}

// ----------------------------------------------------- instance norm final
__global__ __launch_bounds__(384) void k_infin(const float* __restrict__ s, const float* __restrict__ s2,
                                               float* __restrict__ mr){
  const int i = threadIdx.x;
  const float mean = s[i]*(1.f/16384.f);
  const float var  = s2[i]*(1.f/16384.f) - mean*mean;
  mr[i]     = mean;
  mr[384+i] = rsqrtf(var + 1e-5f);
}

// mode 1: lrelu(norm) -> bf16 ; mode 2: norm + residual(bf16) -> bf16
__global__ __launch_bounds__(256) void k_inapply(const u16* __restrict__ craw, const float* __restrict__ mr,
                                                 const u16* __restrict__ resid, u16* __restrict__ outp,
                                                 const int mode){
  const int gid = blockIdx.x*256 + threadIdx.x;
  const size_t base = (size_t)gid*8;
  const int mrow = gid/24;
  const int c0 = (gid%24)*8;
  const int b = mrow >> 14;
  const uint4 rv = *(const uint4*)(craw + base);
  float vv[8] = {blo(rv.x),bhi(rv.x),blo(rv.y),bhi(rv.y),blo(rv.z),bhi(rv.z),blo(rv.w),bhi(rv.w)};
  uint4 xv;
  float rr[8];
  if (mode == 2){
    xv = *(const uint4*)(resid + base);
    rr[0]=blo(xv.x); rr[1]=bhi(xv.x); rr[2]=blo(xv.y); rr[3]=bhi(xv.y);
    rr[4]=blo(xv.z); rr[5]=bhi(xv.z); rr[6]=blo(xv.w); rr[7]=bhi(xv.w);
  }
  unsigned pk[4];
  #pragma unroll
  for (int k2=0;k2<4;k2++){
    const int c = c0 + 2*k2;
    float a0 = (vv[2*k2]   - mr[b*192+c])  * mr[384 + b*192 + c];
    float a1 = (vv[2*k2+1] - mr[b*192+c+1])* mr[384 + b*192 + c+1];
    if (mode == 1){ a0 = a0 > 0.f ? a0 : 0.01f*a0; a1 = a1 > 0.f ? a1 : 0.01f*a1; }
    else          { a0 += rr[2*k2]; a1 += rr[2*k2+1]; }
    pk[k2] = pack2(a0, a1);
  }
  *(uint4*)(outp + base) = make_uint4(pk[0],pk[1],pk[2],pk[3]);
}

// ------------------------------------- scrambled reshape + LayerNorm(192)
__global__ __launch_bounds__(128) void k_ln(const u16* __restrict__ F, const u16* __restrict__ g,
                                            const u16* __restrict__ bb, u16* __restrict__ xn){
  __shared__ u16 S[192*128];
  const int tid = threadIdx.x;
  const int b = blockIdx.y;
  const int l0 = blockIdx.x*128;
  const u16* Fb = F + (size_t)b*3145728;
  for (int qi = tid; qi < 3072; qi += 128){
    int c = qi >> 4, o = (qi & 15)*8;
    *(uint4*)&S[c*128 + o] = *(const uint4*)(Fb + (size_t)c*16384 + l0 + o);
  }
  __syncthreads();
  float sum = 0.f, sq = 0.f;
  for (int c=0;c<192;c++){ float v = b2f(S[c*128 + tid]); sum += v; sq += v*v; }
  const float mean = sum*(1.f/192.f);
  const float rs = rsqrtf(sq*(1.f/192.f) - mean*mean + 1e-5f);
  u16* dst = xn + ((size_t)(b*16384 + l0 + tid))*192;
  for (int c0=0;c0<192;c0+=8){
    unsigned pk[4];
    #pragma unroll
    for (int k2=0;k2<4;k2++){
      int c = c0 + 2*k2;
      float v0 = (b2f(S[(c  )*128+tid]) - mean)*rs*b2f(g[c  ]) + b2f(bb[c  ]);
      float v1 = (b2f(S[(c+1)*128+tid]) - mean)*rs*b2f(g[c+1]) + b2f(bb[c+1]);
      pk[k2] = pack2(v0, v1);
    }
    *(uint4*)(dst + c0) = make_uint4(pk[0],pk[1],pk[2],pk[3]);
  }
}

// ----------------------------------- causal depthwise conv1d (w=4) + silu
__global__ __launch_bounds__(256) void k_conv1d(const u16* __restrict__ u, const u16* __restrict__ w,
                                                const u16* __restrict__ bias, u16* __restrict__ up){
  const int gid = blockIdx.x*256 + threadIdx.x;
  const int mrow = gid/48, d8 = (gid%48)*8;
  const int l = mrow & 16383;
  float acc[8];
  #pragma unroll
  for (int k=0;k<8;k++) acc[k] = b2f(bias[d8+k]);
  float wk[4][8];
  #pragma unroll
  for (int dd=0;dd<8;dd++){
    uint2 tw = *(const uint2*)(w + (size_t)(d8+dd)*4);
    wk[0][dd]=blo(tw.x); wk[1][dd]=bhi(tw.x); wk[2][dd]=blo(tw.y); wk[3][dd]=bhi(tw.y);
  }
  #pragma unroll
  for (int k=0;k<4;k++){
    if (l - 3 + k < 0) continue;
    uint4 tv = *(const uint4*)(u + ((size_t)(mrow-3+k))*384 + d8);
    float uv[8] = {blo(tv.x),bhi(tv.x),blo(tv.y),bhi(tv.y),blo(tv.z),bhi(tv.z),blo(tv.w),bhi(tv.w)};
    #pragma unroll
    for (int dd=0;dd<8;dd++) acc[dd] += uv[dd]*wk[k][dd];
  }
  unsigned pk[4];
  #pragma unroll
  for (int k2=0;k2<4;k2++){
    float a0 = acc[2*k2], a1 = acc[2*k2+1];
    a0 = a0/(1.f + __expf(-a0));
    a1 = a1/(1.f + __expf(-a1));
    pk[k2] = pack2(a0, a1);
  }
  *(uint4*)(up + (size_t)mrow*384 + d8) = make_uint4(pk[0],pk[1],pk[2],pk[3]);
}

// --------------------------------------------- selective scan, chunked
// thread-per-d, 16 states in registers. 256 chunks x 64 steps.
__global__ __launch_bounds__(192) void k_scan1(const float* __restrict__ xdb, const u16* __restrict__ up,
                                               const u16* __restrict__ dtw, const u16* __restrict__ dtb,
                                               const u16* __restrict__ alog,
                                               float* __restrict__ P, float* __restrict__ Q){
  __shared__ float xdbS[64*44];
  const int tid = threadIdx.x;
  const int chunk = blockIdx.x, b = blockIdx.y;
  const int d = blockIdx.z*192 + tid;
  const size_t mbase = (size_t)b*16384 + chunk*64;
  const float* xs = xdb + mbase*44;
  for (int qi=tid; qi<704; qi+=192)
    *(float4*)&xdbS[qi*4] = *(const float4*)(xs + (size_t)qi*4);
  float w[12];
  #pragma unroll
  for (int i=0;i<12;i++) w[i] = b2f(dtw[d*12+i]);
  const float dtbv = b2f(dtb[d]);
  float Av[16];
  #pragma unroll
  for (int s=0;s<16;s++) Av[s] = -__expf(b2f(alog[d*16+s]));
  float pp[16], qq[16];
  #pragma unroll
  for (int s=0;s<16;s++){ pp[s]=1.f; qq[s]=0.f; }
  const u16* uptr = up + mbase*384 + d;
  __syncthreads();
  for (int l=0;l<64;l++){
    const float* row = &xdbS[l*44];
    const float4 r0 = *(const float4*)(row);
    const float4 r1 = *(const float4*)(row+4);
    const float4 r2 = *(const float4*)(row+8);
    float a = dtbv + r0.x*w[0]+r0.y*w[1]+r0.z*w[2]+r0.w*w[3]
                   + r1.x*w[4]+r1.y*w[5]+r1.z*w[6]+r1.w*w[7]
                   + r2.x*w[8]+r2.y*w[9]+r2.z*w[10]+r2.w*w[11];
    const float dl = a > 20.f ? a : __logf(1.f + __expf(a));
    const float uv = b2f(uptr[(size_t)l*384]);
    const float dlu = dl*uv;
    const float4 B0 = *(const float4*)(row+12);
    const float4 B1 = *(const float4*)(row+16);
    const float4 B2 = *(const float4*)(row+20);
    const float4 B3 = *(const float4*)(row+24);
    const float Bv[16] = {B0.x,B0.y,B0.z,B0.w,B1.x,B1.y,B1.z,B1.w,
                          B2.x,B2.y,B2.z,B2.w,B3.x,B3.y,B3.z,B3.w};
    #pragma unroll
    for (int s=0;s<16;s++){
      const float as = __expf(dl*Av[s]);
      pp[s] *= as;
      qq[s] = as*qq[s] + dlu*Bv[s];
    }
  }
  const size_t o = (((size_t)b*256 + chunk)*384 + d)*16;
  float* Po = P + o; float* Qo = Q + o;
  *(float4*)(Po+ 0) = make_float4(pp[0],pp[1],pp[2],pp[3]);
  *(float4*)(Po+ 4) = make_float4(pp[4],pp[5],pp[6],pp[7]);
  *(float4*)(Po+ 8) = make_float4(pp[8],pp[9],pp[10],pp[11]);
  *(float4*)(Po+12) = make_float4(pp[12],pp[13],pp[14],pp[15]);
  *(float4*)(Qo+ 0) = make_float4(qq[0],qq[1],qq[2],qq[3]);
  *(float4*)(Qo+ 4) = make_float4(qq[4],qq[5],qq[6],qq[7]);
  *(float4*)(Qo+ 8) = make_float4(qq[8],qq[9],qq[10],qq[11]);
  *(float4*)(Qo+12) = make_float4(qq[12],qq[13],qq[14],qq[15]);
}

__global__ __launch_bounds__(256) void k_scan2(const float* __restrict__ P, const float* __restrict__ Q,
                                               float* __restrict__ hin){
  const int gid = blockIdx.x*256 + threadIdx.x;      // 12288
  const int b = gid / 6144, ds = gid % 6144;
  const size_t base = (size_t)b*1572864 + ds;
  float h = 0.f;
  for (int g2=0; g2<256; ++g2){
    const size_t idx = base + (size_t)g2*6144;
    hin[idx] = h;
    h = P[idx]*h + Q[idx];
  }
}

__global__ __launch_bounds__(192) void k_scan3(const float* __restrict__ xdb, const u16* __restrict__ up,
                                               const u16* __restrict__ zb,
                                               const u16* __restrict__ dtw, const u16* __restrict__ dtb,
                                               const u16* __restrict__ alog, const u16* __restrict__ dp,
                                               const float* __restrict__ hin, u16* __restrict__ yg){
  __shared__ float xdbS[64*44];
  const int tid = threadIdx.x;
  const int chunk = blockIdx.x, b = blockIdx.y;
  const int d = blockIdx.z*192 + tid;
  const size_t mbase = (size_t)b*16384 + chunk*64;
  const float* xs = xdb + mbase*44;
  for (int qi=tid; qi<704; qi+=192)
    *(float4*)&xdbS[qi*4] = *(const float4*)(xs + (size_t)qi*4);
  float w[12];
  #pragma unroll
  for (int i=0;i<12;i++) w[i] = b2f(dtw[d*12+i]);
  const float dtbv = b2f(dtb[d]);
  float Av[16];
  #pragma unroll
  for (int s=0;s<16;s++) Av[s] = -__expf(b2f(alog[d*16+s]));
  const float Dv = b2f(dp[d]);
  float h[16];
  {
    const float* hi = hin + (((size_t)b*256 + chunk)*384 + d)*16;
    const float4 h0 = *(const float4*)(hi+0);
    const float4 h1 = *(const float4*)(hi+4);
    const float4 h2 = *(const float4*)(hi+8);
    const float4 h3 = *(const float4*)(hi+12);
    h[0]=h0.x;h[1]=h0.y;h[2]=h0.z;h[3]=h0.w;
    h[4]=h1.x;h[5]=h1.y;h[6]=h1.z;h[7]=h1.w;
    h[8]=h2.x;h[9]=h2.y;h[10]=h2.z;h[11]=h2.w;
    h[12]=h3.x;h[13]=h3.y;h[14]=h3.z;h[15]=h3.w;
  }
  const u16* uptr = up + mbase*384 + d;
  const u16* zptr = zb + mbase*384 + d;
  u16* yptr = yg + mbase*384 + d;
  __syncthreads();
  for (int l=0;l<64;l++){
    const float* row = &xdbS[l*44];
    const float4 r0 = *(const float4*)(row);
    const float4 r1 = *(const float4*)(row+4);
    const float4 r2 = *(const float4*)(row+8);
    float a = dtbv + r0.x*w[0]+r0.y*w[1]+r0.z*w[2]+r0.w*w[3]
                   + r1.x*w[4]+r1.y*w[5]+r1.z*w[6]+r1.w*w[7]
                   + r2.x*w[8]+r2.y*w[9]+r2.z*w[10]+r2.w*w[11];
    const float dl = a > 20.f ? a : __logf(1.f + __expf(a));
    const float uv = b2f(uptr[(size_t)l*384]);
    const float dlu = dl*uv;
    const float4 B0 = *(const float4*)(row+12);
    const float4 B1 = *(const float4*)(row+16);
    const float4 B2 = *(const float4*)(row+20);
    const float4 B3 = *(const float4*)(row+24);
    const float4 C0 = *(const float4*)(row+28);
    const float4 C1 = *(const float4*)(row+32);
    const float4 C2 = *(const float4*)(row+36);
    const float4 C3 = *(const float4*)(row+40);
    const float Bv[16] = {B0.x,B0.y,B0.z,B0.w,B1.x,B1.y,B1.z,B1.w,
                          B2.x,B2.y,B2.z,B2.w,B3.x,B3.y,B3.z,B3.w};
    const float Cv[16] = {C0.x,C0.y,C0.z,C0.w,C1.x,C1.y,C1.z,C1.w,
                          C2.x,C2.y,C2.z,C2.w,C3.x,C3.y,C3.z,C3.w};
    float ct = 0.f;
    #pragma unroll
    for (int s=0;s<16;s++){
      const float as = __expf(dl*Av[s]);
      h[s] = as*h[s] + dlu*Bv[s];
      ct += h[s]*Cv[s];
    }
    const float yv = ct + uv*Dv;
    const float zv = b2f(zptr[(size_t)l*384]);
    yptr[(size_t)l*384] = f2b(yv * (zv/(1.f + __expf(-zv))));
  }
}

// ---------------------------------------------------------------------------
extern "C" void kernel_launch(void* const* d_in, const int* in_sizes, int n_in,
                              void* d_out, int out_size, void* d_ws, size_t ws_size,
                              hipStream_t stream){
  (void)in_sizes; (void)n_in; (void)out_size;
  const u16* x = (const u16*)d_in[0];
  u16* outp = (u16*)d_out;

  char* ws = (char*)d_ws;
  size_t off = 0;
  auto alloc = [&](size_t bytes)->void*{
    void* p = (void*)(ws + off);
    off += (bytes + 255) & ~(size_t)255;
    return p;
  };
  int*   cnt   = (int*)  alloc(256);
  u16*   zp    = (u16*)  alloc(512);
  float* stats = (float*)alloc((size_t)3072*4);
  u16*   wc    = (u16*)  alloc((size_t)252288*2);       // small canon tensors
  u16*   Bw1   = (u16*)  alloc((size_t)995328*2);
  u16*   Bw2   = (u16*)  alloc((size_t)995328*2);
  u16*   xc    = (u16*)  alloc((size_t)MTOT*192*2);     // canon x; -> xdb
  u16*   craw  = (u16*)  alloc((size_t)MTOT*192*2);     // conv out; -> xnorm
  u16*   bx    = (u16*)  alloc((size_t)MTOT*192*2);     // x1/xc2; -> hin
  u16*   ubuf  = (u16*)  alloc((size_t)MTOT*384*2);     // u; -> P,Q
  u16*   zbuf  = (u16*)  alloc((size_t)MTOT*384*2);
  u16*   upost = (u16*)  alloc((size_t)MTOT*384*2);     // silu(conv1d); -> yg (in-place safe)
  const size_t NEEDED = off;

  if (ws_size < NEEDED){
    k_diag<<<1,1,0,stream>>>((float*)d_out, (float)(ws_size >> 20));
    return;
  }

  u16* xnorm = craw;
  float* xdb = (float*)xc;
  float* P   = (float*)ubuf;
  float* Q   = (float*)(ubuf + 6291456);   // +12,582,912 bytes
  float* hin = (float*)bx;
  u16*   yg  = upost;

  float* sum1 = stats;        float* sq1 = stats+384;  float* mr1 = stats+768;
  float* sum2 = stats+1536;   float* sq2 = stats+1920; float* mr2 = stats+2304;

  SmallCvt sc;
  const int srcIdx[13] = {2,4,5,6,7,8,9,10,11,12,13,14,15};
  const int ns[13]     = {192,192,192,192,147456,1536,384,16896,4608,384,6144,384,73728};
  const int offs[13]   = {0,192,384,576,768,148224,149760,150144,167040,171648,172032,178176,178560};
  for (int i=0;i<13;i++){ sc.src[i]=d_in[srcIdx[i]]; sc.n[i]=ns[i]; sc.off[i]=offs[i]; }
  const u16 *c1b=wc+0, *c2b=wc+192, *lng=wc+384, *lnb=wc+576, *ipw=wc+768,
            *c1dw=wc+148224, *c1db=wc+149760, *xpw=wc+150144, *dtw=wc+167040,
            *dtb=wc+171648, *alog=wc+172032, *dp=wc+178176, *opw=wc+178560;

  k_init<<<12,256,0,stream>>>(cnt, (float*)zp, stats);
  k_probe<<<1,256,0,stream>>>(x, cnt);
  k_cvt<<<3072,256,0,stream>>>(d_in[0], xc, MTOT*192, cnt);
  k_cvt_small<<<dim3(72,13),256,0,stream>>>(sc, wc, cnt);
  k_wt<<<7776,256,0,stream>>>(d_in[1], d_in[3], Bw1, Bw2, cnt);

  k_conv<<<dim3(256,3),256,0,stream>>>(xc, Bw1, c1b, craw, sum1, sq1);
  k_infin<<<1,384,0,stream>>>(sum1, sq1, mr1);
  k_inapply<<<3072,256,0,stream>>>(craw, mr1, xc, bx, 1);
  k_conv<<<dim3(256,3),256,0,stream>>>(bx, Bw2, c2b, craw, sum2, sq2);
  k_infin<<<1,384,0,stream>>>(sum2, sq2, mr2);
  k_inapply<<<3072,256,0,stream>>>(craw, mr2, xc, bx, 2);

  k_ln<<<dim3(128,2),128,0,stream>>>(bx, lng, lnb, xnorm);
  k_gemm<0><<<dim3(256,12),256,0,stream>>>(xnorm, ipw, 192, 768, ubuf, zbuf, zp, cnt);
  k_conv1d<<<6144,256,0,stream>>>(ubuf, c1dw, c1db, upost);
  k_gemm<1><<<dim3(256,1),256,0,stream>>>(upost, xpw, 384, 44, xdb, nullptr, zp, cnt);
  k_scan1<<<dim3(256,2,2),192,0,stream>>>(xdb, upost, dtw, dtb, alog, P, Q);
  k_scan2<<<48,256,0,stream>>>(P, Q, hin);
  k_scan3<<<dim3(256,2,2),192,0,stream>>>(xdb, upost, zbuf, dtw, dtb, alog, dp, hin, yg);
  k_gemm<2><<<dim3(256,3),256,0,stream>>>(yg, opw, 384, 192, outp, nullptr, zp, cnt);
}